// Round 5
// baseline (737.887 us; speedup 1.0000x reference)
//
#include <hip/hip_runtime.h>
#include <cstdint>
#include <cmath>

#define T_ 2048
#define E_ 4096
#define H_ 16
#define D_ 256
#define NF 32   // rotary freq count (R/2)

typedef int v4i  __attribute__((ext_vector_type(4)));

__device__ __forceinline__ int dot4(int a, int b, int c) {
#if __has_builtin(__builtin_amdgcn_sdot4)
  return __builtin_amdgcn_sdot4(a, b, c, false);
#else
  c += ((a << 24) >> 24) * ((b << 24) >> 24);
  c += ((a << 16) >> 24) * ((b << 16) >> 24);
  c += ((a <<  8) >> 24) * ((b <<  8) >> 24);
  c += (a >> 24) * (b >> 24);
  return c;
#endif
}

__device__ __forceinline__ int pack4i(int4 v) {
  return (v.x & 255) | ((v.y & 255) << 8) | ((v.z & 255) << 16) | (v.w << 24);
}

#define GLD_LDS16(g, l)                                                        \
  __builtin_amdgcn_global_load_lds(                                            \
      (const __attribute__((address_space(1))) void*)(g),                      \
      (__attribute__((address_space(3))) void*)(l), 16, 0, 0)

// ---------------- sin/cos table (double-precision, cast to f32) -------------
__global__ void sincos_kernel(float* __restrict__ sinT, float* __restrict__ cosT) {
  int idx = blockIdx.x * 256 + threadIdx.x;   // t*32 + j
  int t = idx >> 5, j = idx & 31;
  float invf = (float)exp(-(double)j * (log(10000.0) / 32.0));
  float ang = (float)t * invf;                // f32 product, matches reference
  sinT[idx] = (float)sin((double)ang);
  cosT[idx] = (float)cos((double)ang);
}

// ---- all 5 repacks (x + 4 weights) in one dispatch: grid (E*E/16/256, 5) ---
__global__ __launch_bounds__(256) void repack5_kernel(
    const int* __restrict__ sx, const int* __restrict__ s1,
    const int* __restrict__ s2, const int* __restrict__ s3,
    const int* __restrict__ s4,
    int8_t* __restrict__ dx, int8_t* __restrict__ d1,
    int8_t* __restrict__ d2, int8_t* __restrict__ d3,
    int8_t* __restrict__ d4) {
  const int w = blockIdx.y;
  if (w == 0 && blockIdx.x >= (T_ * E_ / 16) / 256) return;  // x is 1/2 size
  const int* __restrict__ src =
      (w == 0) ? sx : (w == 1 ? s1 : (w == 2 ? s2 : (w == 3 ? s3 : s4)));
  int8_t* __restrict__ dst =
      (w == 0) ? dx : (w == 1 ? d1 : (w == 2 ? d2 : (w == 3 ? d3 : d4)));
  size_t i = (size_t)blockIdx.x * 256 + threadIdx.x;
  const int4* s = (const int4*)src + i * 4;
  int4 a = s[0], b = s[1], c = s[2], d = s[3];
  int4 o;
  o.x = pack4i(a); o.y = pack4i(b); o.z = pack4i(c); o.w = pack4i(d);
  ((int4*)dst)[i] = o;
}

// =================== MFMA int8 GEMM: QKV projection + fused RoPE ============
// r2-verified structure: grid (T/128, E/128, 3), block 256, wave tile 64x64,
// triple-buffered LDS (48 KB -> 3 blocks/CU), counted vmcnt(4), XOR swizzle
// with pre-swizzled global source. mode 2 (V) writes transposed VT[h][d][t].
// RoPE (d<64) fused into the epilogue via __shfl_xor pair exchange.
__global__ __launch_bounds__(256, 3) void qkv_gemm_mfma(
    const int8_t* __restrict__ x8,
    const int8_t* __restrict__ Wq8, const int* __restrict__ bq,
    const int8_t* __restrict__ Wk8, const int* __restrict__ bk,
    const int8_t* __restrict__ Wv8, const int* __restrict__ bv,
    const float* __restrict__ alpq, const float* __restrict__ betq,
    const float* __restrict__ alpk, const float* __restrict__ betk,
    const float* __restrict__ alpv, const float* __restrict__ betv,
    const float* __restrict__ sinT, const float* __restrict__ cosT,
    int8_t* __restrict__ Q8, int8_t* __restrict__ K8, int8_t* __restrict__ VT)
{
  const int mode = blockIdx.z;
  const int8_t* __restrict__ W = (mode == 0) ? Wq8 : (mode == 1 ? Wk8 : Wv8);
  const int* __restrict__ bs   = (mode == 0) ? bq  : (mode == 1 ? bk  : bv);
  const float alpha = (mode == 0) ? alpq[0] : (mode == 1 ? alpk[0] : alpv[0]);
  const float beta  = (mode == 0) ? betq[0] : (mode == 1 ? betk[0] : betv[0]);

  __shared__ int8_t As[3][8192];
  __shared__ int8_t Bs[3][8192];

  const int tid  = threadIdx.x;
  const int wave = tid >> 6, lane = tid & 63;
  const int wm = wave >> 1, wn = wave & 1;
  const int t0 = blockIdx.x * 128, o0 = blockIdx.y * 128;

  const int srow = lane >> 2;
  const int scol = ((lane & 3) ^ ((lane >> 3) & 3)) * 16;  // pre-swizzled src
  const int col  = lane & 15;
  const int quad = lane >> 4;

  v4i acc[4][4] = {};

  const int8_t* gA0 = x8 + (size_t)(t0 + wave * 32 + srow) * E_ + scol;
  const int8_t* gB0 = W  + (size_t)(o0 + wave * 32 + srow) * E_ + scol;

#define STAGE_QKV(bufi, kt) do {                                               \
    const int e0_ = (kt) * 64;                                                 \
    GLD_LDS16(gA0 + e0_,           As[bufi] + wave * 2048);                    \
    GLD_LDS16(gA0 + e0_ + 16 * E_, As[bufi] + wave * 2048 + 1024);             \
    GLD_LDS16(gB0 + e0_,           Bs[bufi] + wave * 2048);                    \
    GLD_LDS16(gB0 + e0_ + 16 * E_, Bs[bufi] + wave * 2048 + 1024);             \
  } while (0)

  int aoff[4], boff[4];
  #pragma unroll
  for (int i = 0; i < 4; ++i) {
    const int ra = wm * 64 + i * 16 + col;
    aoff[i] = ra * 64 + ((quad ^ ((ra >> 1) & 3)) * 16);
    const int rb = wn * 64 + i * 16 + col;
    boff[i] = rb * 64 + ((quad ^ ((rb >> 1) & 3)) * 16);
  }

  STAGE_QKV(0, 0);
  STAGE_QKV(1, 1);

  int cur = 0;
  for (int kt = 0; kt < 64; ++kt) {
    if (kt == 63) asm volatile("s_waitcnt vmcnt(0)" ::: "memory");
    else          asm volatile("s_waitcnt vmcnt(4)" ::: "memory");
    __builtin_amdgcn_s_barrier();
    if (kt < 62) {
      int nb = cur + 2; if (nb >= 3) nb -= 3;
      STAGE_QKV(nb, kt + 2);
    }
    v4i a[4], b[4];
    #pragma unroll
    for (int i = 0; i < 4; ++i)
      a[i] = *(const v4i*)(As[cur] + aoff[i]);
    #pragma unroll
    for (int j = 0; j < 4; ++j)
      b[j] = *(const v4i*)(Bs[cur] + boff[j]);
    __builtin_amdgcn_s_setprio(1);
    #pragma unroll
    for (int i = 0; i < 4; ++i)
      #pragma unroll
      for (int j = 0; j < 4; ++j)
        acc[i][j] = __builtin_amdgcn_mfma_i32_16x16x64_i8(a[i], b[j], acc[i][j], 0, 0, 0);
    __builtin_amdgcn_s_setprio(0);
    cur = (cur == 2) ? 0 : cur + 1;
  }
#undef STAGE_QKV

  int8_t* __restrict__ dst = (mode == 0) ? Q8 : (mode == 1 ? K8 : VT);
  // rope applies to dd<64 of each head: wave-uniform (o0%256==0 && wn==0)
  const bool ropeWave = (mode < 2) && ((o0 & 128) == 0) && (wn == 0);
  #pragma unroll
  for (int j = 0; j < 4; ++j) {
    const int o  = o0 + wn * 64 + j * 16 + col;
    const int h  = o >> 8;
    const int dd = o & 255;
    const float bb = (float)bs[o];
    const int jj = dd >> 1;
    #pragma unroll
    for (int i = 0; i < 4; ++i) {
      const int tb = t0 + wm * 64 + i * 16 + quad * 4;
      int qb[4];
      #pragma unroll
      for (int r = 0; r < 4; ++r) {
        float v = __fadd_rn(__fmul_rn(alpha, (float)acc[i][j][r]),
                            __fmul_rn(beta, bb));
        v = rintf(v);
        v = fminf(fmaxf(v, -128.0f), 127.0f);
        qb[r] = (int)v;
      }
      if (ropeWave) {
        // lanes col / col^1 hold dd / dd^1 of the same row: exchange via shfl
        #pragma unroll
        for (int r = 0; r < 4; ++r) {
          float y  = (float)qb[r];
          float yo = __shfl_xor(y, 1);
          const int t = tb + r;
          const float s = sinT[t * NF + jj];
          const float c = cosT[t * NF + jj];
          float rv = ((col & 1) == 0)
              ? __fadd_rn(__fmul_rn(y, c), __fmul_rn(-yo, s))
              : __fadd_rn(__fmul_rn(y, c), __fmul_rn(yo, s));
          qb[r] = (int)fminf(fmaxf(truncf(rv), -128.0f), 127.0f);
        }
      }
      if (mode == 2) {
        int packed = (qb[0] & 255) | ((qb[1] & 255) << 8) |
                     ((qb[2] & 255) << 16) | ((qb[3] & 255) << 24);
        *(int*)(dst + ((size_t)h * 256 + dd) * T_ + tb) = packed;
      } else {
        #pragma unroll
        for (int r = 0; r < 4; ++r)
          dst[((size_t)h * T_ + tb + r) * D_ + dd] = (int8_t)qb[r];
      }
    }
  }
}

// =================== MFMA int8 GEMM: output projection =======================
// r2-verified config: grid (T/128, E/128), block 256, triple-buffer, vmcnt(4).
__global__ __launch_bounds__(256, 3) void out_gemm_mfma(
    const int8_t* __restrict__ xa, const int8_t* __restrict__ Wo8,
    const float* __restrict__ b_out, const float* __restrict__ p_aout,
    float* __restrict__ out)
{
  const float alpha = p_aout[0];
  __shared__ int8_t As[3][8192];
  __shared__ int8_t Bs[3][8192];

  const int tid  = threadIdx.x;
  const int wave = tid >> 6, lane = tid & 63;
  const int wm = wave >> 1, wn = wave & 1;
  const int t0 = blockIdx.x * 128, o0 = blockIdx.y * 128;
  const int srow = lane >> 2;
  const int scol = ((lane & 3) ^ ((lane >> 3) & 3)) * 16;
  const int col = lane & 15, quad = lane >> 4;

  v4i acc[4][4] = {};
  const int8_t* gA0 = xa  + (size_t)(t0 + wave * 32 + srow) * E_ + scol;
  const int8_t* gB0 = Wo8 + (size_t)(o0 + wave * 32 + srow) * E_ + scol;

#define STAGE_OUT(bufi, kt) do {                                               \
    const int e0_ = (kt) * 64;                                                 \
    GLD_LDS16(gA0 + e0_,           As[bufi] + wave * 2048);                    \
    GLD_LDS16(gA0 + e0_ + 16 * E_, As[bufi] + wave * 2048 + 1024);             \
    GLD_LDS16(gB0 + e0_,           Bs[bufi] + wave * 2048);                    \
    GLD_LDS16(gB0 + e0_ + 16 * E_, Bs[bufi] + wave * 2048 + 1024);             \
  } while (0)

  int aoff[4], boff[4];
  #pragma unroll
  for (int i = 0; i < 4; ++i) {
    const int ra = wm * 64 + i * 16 + col;
    aoff[i] = ra * 64 + ((quad ^ ((ra >> 1) & 3)) * 16);
    const int rb = wn * 64 + i * 16 + col;
    boff[i] = rb * 64 + ((quad ^ ((rb >> 1) & 3)) * 16);
  }

  STAGE_OUT(0, 0);
  STAGE_OUT(1, 1);

  int cur = 0;
  for (int kt = 0; kt < 64; ++kt) {
    if (kt == 63) asm volatile("s_waitcnt vmcnt(0)" ::: "memory");
    else          asm volatile("s_waitcnt vmcnt(4)" ::: "memory");
    __builtin_amdgcn_s_barrier();
    if (kt < 62) {
      int nb = cur + 2; if (nb >= 3) nb -= 3;
      STAGE_OUT(nb, kt + 2);
    }
    v4i a[4], b[4];
    #pragma unroll
    for (int i = 0; i < 4; ++i)
      a[i] = *(const v4i*)(As[cur] + aoff[i]);
    #pragma unroll
    for (int j = 0; j < 4; ++j)
      b[j] = *(const v4i*)(Bs[cur] + boff[j]);
    __builtin_amdgcn_s_setprio(1);
    #pragma unroll
    for (int i = 0; i < 4; ++i)
      #pragma unroll
      for (int j = 0; j < 4; ++j)
        acc[i][j] = __builtin_amdgcn_mfma_i32_16x16x64_i8(a[i], b[j], acc[i][j], 0, 0, 0);
    __builtin_amdgcn_s_setprio(0);
    cur = (cur == 2) ? 0 : cur + 1;
  }
#undef STAGE_OUT

  #pragma unroll
  for (int j = 0; j < 4; ++j) {
    const int o = o0 + wn * 64 + j * 16 + col;
    const float bb = b_out[o];
    #pragma unroll
    for (int i = 0; i < 4; ++i) {
      #pragma unroll
      for (int r = 0; r < 4; ++r) {
        const int t = t0 + wm * 64 + i * 16 + quad * 4 + r;
        out[(size_t)t * E_ + o] = __fadd_rn(__fmul_rn(alpha, (float)acc[i][j][r]), bb);
      }
    }
  }
}

// =================== split-s attention, kernel A: m/s partials ==============
// grid (8 chunks, 32 qtiles, 16 heads), block 256. chunk = 4 K-tiles of 64.
// K double-buffered (prefetch at iter top, wait at iter end), XOR-swizzled
// Q/K tiles, ONE raw barrier per iteration.
__global__ __launch_bounds__(256) void attn_ms_chunk(
    const int8_t* __restrict__ Q8, const int8_t* __restrict__ K8,
    const float* __restrict__ p_aqk,
    float* __restrict__ mPart, float* __restrict__ sPart)
{
  const int ch = blockIdx.x;
  const int qi = blockIdx.y;
  const int h  = blockIdx.z;
  if ((ch << 2) > qi) return;               // chunk beyond causal diagonal

  __shared__ int8_t Qs[4 * 4096];           // 16 KB, swizzled
  __shared__ int8_t Ks[2][16384];           // K double-buffer, swizzled
  __shared__ float  mred[64][2];
  __shared__ float  sred[64][2];

  const int t0  = qi * 64;
  const int tid = threadIdx.x;
  const int wave = tid >> 6, lane = tid & 63;
  const int wm = wave >> 1, wn = wave & 1;
  const int col = lane & 15, quad = lane >> 4;
  const int srow = lane >> 2;
  const int scol = ((lane & 3) ^ ((lane >> 3) & 3)) * 16;  // pre-swizzled src
  const float aqk = p_aqk[0] * 0.0625f;

  const int it0 = ch * 4;
  const int it1 = (it0 + 3 < qi) ? (it0 + 3) : qi;

  // stage Q + first K tile; drain; barrier
  {
    const int8_t* g = Q8 + ((size_t)h * T_ + t0 + wave * 16 + srow) * D_ + scol;
    #pragma unroll
    for (int c = 0; c < 4; ++c)
      GLD_LDS16(g + c * 64, Qs + c * 4096 + wave * 1024);
    const int8_t* gk = K8 + ((size_t)h * T_ + it0 * 64 + wave * 16 + srow) * D_ + scol;
    #pragma unroll
    for (int c = 0; c < 4; ++c)
      GLD_LDS16(gk + c * 64, Ks[0] + c * 4096 + wave * 1024);
  }
  asm volatile("s_waitcnt vmcnt(0)" ::: "memory");
  __builtin_amdgcn_s_barrier();

  int qoff[2], koff[2];
  #pragma unroll
  for (int i = 0; i < 2; ++i) {
    const int ra = wm * 32 + i * 16 + col;
    qoff[i] = ra * 64 + ((quad ^ ((ra >> 1) & 3)) * 16);
    const int rb = wn * 32 + i * 16 + col;
    koff[i] = rb * 64 + ((quad ^ ((rb >> 1) & 3)) * 16);
  }

  float m[8], sm[8];
  #pragma unroll
  for (int u = 0; u < 8; ++u) { m[u] = -INFINITY; sm[u] = 0.0f; }

  int cur = 0;
  for (int it = it0; it <= it1; ++it) {
    const int s0 = it * 64;
    if (it < it1) {                         // prefetch next K tile
      const int8_t* g = K8 + ((size_t)h * T_ + (it + 1) * 64 + wave * 16 + srow) * D_ + scol;
      #pragma unroll
      for (int c = 0; c < 4; ++c)
        GLD_LDS16(g + c * 64, Ks[cur ^ 1] + c * 4096 + wave * 1024);
    }
    v4i accS[2][2] = {};
    #pragma unroll
    for (int c = 0; c < 4; ++c) {
      v4i a[2], b[2];
      #pragma unroll
      for (int i = 0; i < 2; ++i)
        a[i] = *(const v4i*)(Qs + c * 4096 + qoff[i]);
      #pragma unroll
      for (int j = 0; j < 2; ++j)
        b[j] = *(const v4i*)(Ks[cur] + c * 4096 + koff[j]);
      #pragma unroll
      for (int i = 0; i < 2; ++i)
        #pragma unroll
        for (int j = 0; j < 2; ++j)
          accS[i][j] = __builtin_amdgcn_mfma_i32_16x16x64_i8(a[i], b[j], accS[i][j], 0, 0, 0);
    }
    const bool diag = (s0 == t0);
    #pragma unroll
    for (int i = 0; i < 2; ++i) {
      #pragma unroll
      for (int r = 0; r < 4; ++r) {
        const int ri = i * 4 + r;
        const int qrow = t0 + wm * 32 + i * 16 + quad * 4 + r;
        #pragma unroll
        for (int j = 0; j < 2; ++j) {
          const int s = s0 + wn * 32 + j * 16 + col;
          if (!diag || s <= qrow) {
            float l = __fmul_rn(aqk, (float)accS[i][j][r]);
            if (l > m[ri]) { sm[ri] = sm[ri] * expf(m[ri] - l) + 1.0f; m[ri] = l; }
            else           { sm[ri] += expf(l - m[ri]); }
          }
        }
      }
    }
    // prefetch complete + all reads of Ks[cur] done (they precede this point)
    asm volatile("s_waitcnt vmcnt(0)" ::: "memory");
    __builtin_amdgcn_s_barrier();
    cur ^= 1;
  }

  // reduce over the 16 col-lanes (NaN-guarded for fully-masked lanes)
  #pragma unroll
  for (int u = 0; u < 8; ++u) {
    #pragma unroll
    for (int off = 1; off < 16; off <<= 1) {
      float om = __shfl_xor(m[u], off);
      float os = __shfl_xor(sm[u], off);
      float mm = fmaxf(m[u], om);
      float e1 = (m[u] == mm) ? 1.0f : expf(m[u] - mm);
      float e2 = (om   == mm) ? 1.0f : expf(om - mm);
      sm[u] = sm[u] * e1 + os * e2;
      m[u] = mm;
    }
  }
  __syncthreads();
  if (col == 0) {
    #pragma unroll
    for (int u = 0; u < 8; ++u) {
      int row = wm * 32 + (u >> 2) * 16 + quad * 4 + (u & 3);
      mred[row][wn] = m[u];
      sred[row][wn] = sm[u];
    }
  }
  __syncthreads();
  if (col == 0 && wn == 0) {
    #pragma unroll
    for (int u = 0; u < 8; ++u) {
      int row = wm * 32 + (u >> 2) * 16 + quad * 4 + (u & 3);
      float m0 = mred[row][0], m1 = mred[row][1];
      float sa = sred[row][0], sb = sred[row][1];
      float mm = fmaxf(m0, m1);
      float e0 = (m0 == mm) ? 1.0f : expf(m0 - mm);
      float e1 = (m1 == mm) ? 1.0f : expf(m1 - mm);
      size_t base = (((size_t)h * 32 + qi) * 64 + row) * 8 + ch;
      mPart[base] = mm;
      sPart[base] = __fadd_rn(__fmul_rn(sa, e0), __fmul_rn(sb, e1));
    }
  }
}

// =================== kernel C: P quantize + PV int32 partials ===============
// grid (2 chunks, 32 qtiles, 16 heads). chunk = 16 K-tiles. heavy-first.
// Redesign: K double-buffered in LDS (prefetch at iter top, waited at iter
// end), V loaded DIRECTLY into registers (issued early, hidden under
// QK+softmax), Ps padded to 80B stride, XOR-swizzled Q/K. 2 barriers/iter
// (was 5), no vmcnt(0) drain mid-iteration.
__global__ __launch_bounds__(256) void attn_pv_chunk(
    const int8_t* __restrict__ Q8, const int8_t* __restrict__ K8,
    const int8_t* __restrict__ VT,
    const float* __restrict__ p_aqk,
    const float* __restrict__ mPart, const float* __restrict__ sPart,
    int* __restrict__ P0, int* __restrict__ P1)
{
  const int cc = blockIdx.x;
  const int qi = 31 - blockIdx.y;             // heavy q-tiles dispatched first
  const int h  = blockIdx.z;
  if (cc == 1 && qi < 16) return;

  __shared__ int8_t Qs[4 * 4096];             // 16 KB, swizzled
  __shared__ int8_t Ks[2][16384];             // 32 KB K double-buffer, swizzled
  __shared__ int8_t Ps[64][80];               // padded: kills 8-way conflict

  const int t0  = qi * 64;
  const int tid = threadIdx.x;
  const int wave = tid >> 6, lane = tid & 63;
  const int wm = wave >> 1, wn = wave & 1;
  const int col = lane & 15, quad = lane >> 4;
  const int srow = lane >> 2;
  const int scol = ((lane & 3) ^ ((lane >> 3) & 3)) * 16;  // pre-swizzled src
  const float aqk = p_aqk[0] * 0.0625f;

  const int it0 = cc * 16;
  const int it1 = (it0 + 15 < qi) ? (it0 + 15) : qi;

  // stage Q + first K tile
  {
    const int8_t* g = Q8 + ((size_t)h * T_ + t0 + wave * 16 + srow) * D_ + scol;
    #pragma unroll
    for (int c = 0; c < 4; ++c)
      GLD_LDS16(g + c * 64, Qs + c * 4096 + wave * 1024);
    const int8_t* gk = K8 + ((size_t)h * T_ + it0 * 64 + wave * 16 + srow) * D_ + scol;
    #pragma unroll
    for (int c = 0; c < 4; ++c)
      GLD_LDS16(gk + c * 64, Ks[0] + c * 4096 + wave * 1024);
  }

  // fold chunk partials into final m/s (identical order to original combine)
  float mF[8], sF[8];
  const int nch = (qi >> 2) + 1;
  #pragma unroll
  for (int u = 0; u < 8; ++u) {
    const int row = wm * 32 + (u >> 2) * 16 + quad * 4 + (u & 3);
    const float* mp = mPart + (((size_t)h * 32 + qi) * 64 + row) * 8;
    const float* sp = sPart + (((size_t)h * 32 + qi) * 64 + row) * 8;
    float m = mp[0], s = sp[0];
    for (int c = 1; c < nch; ++c) {
      float mc = mp[c], sc = sp[c];
      float mm = fmaxf(m, mc);
      float e1 = (m  == mm) ? 1.0f : expf(m - mm);
      float e2 = (mc == mm) ? 1.0f : expf(mc - mm);
      s = __fadd_rn(__fmul_rn(s, e1), __fmul_rn(sc, e2));
      m = mm;
    }
    mF[u] = m;
    sF[u] = s;
  }

  asm volatile("s_waitcnt vmcnt(0)" ::: "memory");
  __builtin_amdgcn_s_barrier();               // Q + K(it0) staged everywhere

  int qoff[2], koff[2];
  #pragma unroll
  for (int i = 0; i < 2; ++i) {
    const int ra = wm * 32 + i * 16 + col;
    qoff[i] = ra * 64 + ((quad ^ ((ra >> 1) & 3)) * 16);
    const int rb = wn * 32 + i * 16 + col;
    koff[i] = rb * 64 + ((quad ^ ((rb >> 1) & 3)) * 16);
  }

  v4i pv[2][8] = {};
  int cur = 0;
  for (int it = it0; it <= it1; ++it) {
    const int s0 = it * 64;
    // V fragments -> registers (compiler-managed waits; hidden under QK+softmax)
    v4i vb[8];
    #pragma unroll
    for (int dt = 0; dt < 8; ++dt)
      vb[dt] = *(const v4i*)(VT + ((size_t)h * 256 + wn * 128 + dt * 16 + col) * T_
                             + s0 + quad * 16);
    // prefetch next K tile into the other buffer
    if (it < it1) {
      const int8_t* g = K8 + ((size_t)h * T_ + (it + 1) * 64 + wave * 16 + srow) * D_ + scol;
      #pragma unroll
      for (int c = 0; c < 4; ++c)
        GLD_LDS16(g + c * 64, Ks[cur ^ 1] + c * 4096 + wave * 1024);
    }
    // QK^T from Ks[cur]
    v4i accS[2][2] = {};
    #pragma unroll
    for (int c = 0; c < 4; ++c) {
      v4i a[2], b[2];
      #pragma unroll
      for (int i = 0; i < 2; ++i)
        a[i] = *(const v4i*)(Qs + c * 4096 + qoff[i]);
      #pragma unroll
      for (int j = 0; j < 2; ++j)
        b[j] = *(const v4i*)(Ks[cur] + c * 4096 + koff[j]);
      #pragma unroll
      for (int i = 0; i < 2; ++i)
        #pragma unroll
        for (int j = 0; j < 2; ++j)
          accS[i][j] = __builtin_amdgcn_mfma_i32_16x16x64_i8(a[i], b[j], accS[i][j], 0, 0, 0);
    }
    // softmax -> Ps (exact ref order)
    const bool diag = (s0 == t0);
    #pragma unroll
    for (int i = 0; i < 2; ++i) {
      #pragma unroll
      for (int r = 0; r < 4; ++r) {
        const int ri = i * 4 + r;
        const int qrow = t0 + wm * 32 + i * 16 + quad * 4 + r;
        #pragma unroll
        for (int j = 0; j < 2; ++j) {
          const int s = s0 + wn * 32 + j * 16 + col;
          int q = 0;
          if (!diag || s <= qrow) {
            float l = __fmul_rn(aqk, (float)accS[i][j][r]);
            float p = expf(l - mF[ri]) / sF[ri];       // division first (ref order)
            q = (int)rintf(__fmul_rn(p, 127.0f));
          }
          Ps[wm * 32 + i * 16 + quad * 4 + r][wn * 32 + j * 16 + col] = (int8_t)q;
        }
      }
    }
    asm volatile("s_waitcnt lgkmcnt(0)" ::: "memory");  // Ps writes landed
    __builtin_amdgcn_s_barrier();                       // Ps visible; NO vmcnt drain
    // PV: A from Ps (LDS), B from V registers
    v4i a2[2];
    #pragma unroll
    for (int i = 0; i < 2; ++i)
      a2[i] = *(const v4i*)&Ps[wm * 32 + i * 16 + col][quad * 16];
    #pragma unroll
    for (int i = 0; i < 2; ++i)
      #pragma unroll
      for (int dt = 0; dt < 8; ++dt)
        pv[i][dt] = __builtin_amdgcn_mfma_i32_16x16x64_i8(a2[i], vb[dt], pv[i][dt], 0, 0, 0);
    // K prefetch complete; Ps/K reads done before next iter's writes
    asm volatile("s_waitcnt vmcnt(0)" ::: "memory");
    __builtin_amdgcn_s_barrier();
    cur ^= 1;
  }

  // store int32 partial tile
  int* __restrict__ dst = (cc == 0)
      ? P0 + (((size_t)h * 32 + qi) << 14)
      : P1 + (((size_t)h * 16 + (qi - 16)) << 14);
  #pragma unroll
  for (int i = 0; i < 2; ++i) {
    #pragma unroll
    for (int r = 0; r < 4; ++r) {
      const int trow = wm * 32 + i * 16 + quad * 4 + r;
      #pragma unroll
      for (int dt = 0; dt < 8; ++dt) {
        const int d = wn * 128 + dt * 16 + col;
        dst[trow * 256 + d] = pv[i][dt][r];
      }
    }
  }
}

// =================== kernel D: sum partials + quantize -> attn8 =============
__global__ __launch_bounds__(256) void attn_pv_combine(
    const int* __restrict__ P0, const int* __restrict__ P1,
    const float* __restrict__ p_apv, int8_t* __restrict__ attn8)
{
  const float apv = p_apv[0];
  int idx = blockIdx.x * 256 + threadIdx.x;   // h*(32*64*64) + qi*(64*64) + row*64 + d4
  int d4  = idx & 63;
  int row = (idx >> 6) & 63;
  int qi  = (idx >> 12) & 31;
  int h   = idx >> 17;
  size_t off = (((size_t)h * 32 + qi) << 14) + row * 256 + d4 * 4;
  int4 a = *(const int4*)(P0 + off);
  if (qi >= 16) {
    size_t off1 = (((size_t)h * 16 + (qi - 16)) << 14) + row * 256 + d4 * 4;
    int4 b1 = *(const int4*)(P1 + off1);
    a.x += b1.x; a.y += b1.y; a.z += b1.z; a.w += b1.w;
  }
  int q[4];
  int vv[4] = {a.x, a.y, a.z, a.w};
  #pragma unroll
  for (int r = 0; r < 4; ++r) {
    float y = rintf(__fmul_rn(apv, (float)vv[r]));
    y = fminf(fmaxf(y, -128.0f), 127.0f);
    q[r] = (int)y;
  }
  int packed = (q[0] & 255) | ((q[1] & 255) << 8) | ((q[2] & 255) << 16) | ((q[3] & 255) << 24);
  int t = qi * 64 + row;
  *(int*)(attn8 + (size_t)t * E_ + h * D_ + d4 * 4) = packed;
}

// =================== MFMA attention (small-ws fallback path) ================
__global__ __launch_bounds__(256) void attn_mfma(
    const int8_t* __restrict__ Q8, const int8_t* __restrict__ K8,
    const int8_t* __restrict__ VT,
    const float* __restrict__ p_aqk, const float* __restrict__ p_apv,
    int8_t* __restrict__ attn8)
{
  __shared__ int8_t Qs[4 * 4096];
  __shared__ int8_t KVs[16384];
  __shared__ int8_t Ps[64][64];
  __shared__ float  mred[64][2];
  __shared__ float  sred[64][2];

  const int h   = blockIdx.y;
  const int t0  = blockIdx.x * 64;
  const int tid = threadIdx.x;
  const int wave = tid >> 6, lane = tid & 63;
  const int wm = wave >> 1, wn = wave & 1;
  const int col = lane & 15, quad = lane >> 4;
  const int srow = lane >> 2, scol = (lane & 3) * 16;
  const float aqk = p_aqk[0] * 0.0625f;
  const float apv = p_apv[0];

  {
    const int8_t* g = Q8 + ((size_t)h * T_ + t0 + wave * 16 + srow) * D_ + scol;
    #pragma unroll
    for (int c = 0; c < 4; ++c)
      GLD_LDS16(g + c * 64, Qs + c * 4096 + wave * 1024);
  }

  const int nt = t0 / 64 + 1;

  float m[8], sm[8];
  #pragma unroll
  for (int u = 0; u < 8; ++u) { m[u] = -INFINITY; sm[u] = 0.0f; }

  for (int it = 0; it < nt; ++it) {
    const int s0 = it * 64;
    __syncthreads();
    {
      const int8_t* g = K8 + ((size_t)h * T_ + s0 + wave * 16 + srow) * D_ + scol;
      #pragma unroll
      for (int c = 0; c < 4; ++c)
        GLD_LDS16(g + c * 64, KVs + c * 4096 + wave * 1024);
    }
    __syncthreads();
    v4i accS[2][2] = {};
    #pragma unroll
    for (int c = 0; c < 4; ++c) {
      v4i a[2], b[2];
      #pragma unroll
      for (int i = 0; i < 2; ++i)
        a[i] = *(const v4i*)(Qs + c * 4096 + (wm * 32 + i * 16 + col) * 64 + quad * 16);
      #pragma unroll
      for (int j = 0; j < 2; ++j)
        b[j] = *(const v4i*)(KVs + c * 4096 + (wn * 32 + j * 16 + col) * 64 + quad * 16);
      #pragma unroll
      for (int i = 0; i < 2; ++i)
        #pragma unroll
        for (int j = 0; j < 2; ++j)
          accS[i][j] = __builtin_amdgcn_mfma_i32_16x16x64_i8(a[i], b[j], accS[i][j], 0, 0, 0);
    }
    const bool diag = (s0 == t0);
    #pragma unroll
    for (int i = 0; i < 2; ++i) {
      #pragma unroll
      for (int r = 0; r < 4; ++r) {
        const int ri = i * 4 + r;
        const int qrow = t0 + wm * 32 + i * 16 + quad * 4 + r;
        #pragma unroll
        for (int j = 0; j < 2; ++j) {
          const int s = s0 + wn * 32 + j * 16 + col;
          if (!diag || s <= qrow) {
            float l = __fmul_rn(aqk, (float)accS[i][j][r]);
            if (l > m[ri]) { sm[ri] = sm[ri] * expf(m[ri] - l) + 1.0f; m[ri] = l; }
            else           { sm[ri] += expf(l - m[ri]); }
          }
        }
      }
    }
  }

  #pragma unroll
  for (int u = 0; u < 8; ++u) {
    #pragma unroll
    for (int off = 1; off < 16; off <<= 1) {
      float om = __shfl_xor(m[u], off);
      float os = __shfl_xor(sm[u], off);
      float mm = fmaxf(m[u], om);
      float e1 = (m[u] == mm) ? 1.0f : expf(m[u] - mm);
      float e2 = (om   == mm) ? 1.0f : expf(om - mm);
      sm[u] = sm[u] * e1 + os * e2;
      m[u] = mm;
    }
  }
  __syncthreads();
  if (col == 0) {
    #pragma unroll
    for (int u = 0; u < 8; ++u) {
      int row = wm * 32 + (u >> 2) * 16 + quad * 4 + (u & 3);
      mred[row][wn] = m[u];
      sred[row][wn] = sm[u];
    }
  }
  __syncthreads();
  float mF[8], sF[8];
  #pragma unroll
  for (int u = 0; u < 8; ++u) {
    int row = wm * 32 + (u >> 2) * 16 + quad * 4 + (u & 3);
    float m0 = mred[row][0], m1 = mred[row][1];
    float sa = sred[row][0], sb = sred[row][1];
    float mm = fmaxf(m0, m1);
    float e0 = (m0 == mm) ? 1.0f : expf(m0 - mm);
    float e1 = (m1 == mm) ? 1.0f : expf(m1 - mm);
    mF[u] = mm;
    sF[u] = __fadd_rn(__fmul_rn(sa, e0), __fmul_rn(sb, e1));
  }

  v4i pv[2][8] = {};
  for (int it = 0; it < nt; ++it) {
    const int s0 = it * 64;
    __syncthreads();
    {
      const int8_t* g = K8 + ((size_t)h * T_ + s0 + wave * 16 + srow) * D_ + scol;
      #pragma unroll
      for (int c = 0; c < 4; ++c)
        GLD_LDS16(g + c * 64, KVs + c * 4096 + wave * 1024);
    }
    __syncthreads();
    v4i accS[2][2] = {};
    #pragma unroll
    for (int c = 0; c < 4; ++c) {
      v4i a[2], b[2];
      #pragma unroll
      for (int i = 0; i < 2; ++i)
        a[i] = *(const v4i*)(Qs + c * 4096 + (wm * 32 + i * 16 + col) * 64 + quad * 16);
      #pragma unroll
      for (int j = 0; j < 2; ++j)
        b[j] = *(const v4i*)(KVs + c * 4096 + (wn * 32 + j * 16 + col) * 64 + quad * 16);
      #pragma unroll
      for (int i = 0; i < 2; ++i)
        #pragma unroll
        for (int j = 0; j < 2; ++j)
          accS[i][j] = __builtin_amdgcn_mfma_i32_16x16x64_i8(a[i], b[j], accS[i][j], 0, 0, 0);
    }
    __syncthreads();
    {
      #pragma unroll
      for (int c = 0; c < 4; ++c) {
        const int drow = (wave * 4 + c) * 16 + srow;
        GLD_LDS16(VT + ((size_t)h * 256 + drow) * T_ + s0 + scol,
                  KVs + (wave * 4 + c) * 1024);
      }
    }
    const bool diag = (s0 == t0);
    #pragma unroll
    for (int i = 0; i < 2; ++i) {
      #pragma unroll
      for (int r = 0; r < 4; ++r) {
        const int ri = i * 4 + r;
        const int qrow = t0 + wm * 32 + i * 16 + quad * 4 + r;
        #pragma unroll
        for (int j = 0; j < 2; ++j) {
          const int s = s0 + wn * 32 + j * 16 + col;
          int q = 0;
          if (!diag || s <= qrow) {
            float l = __fmul_rn(aqk, (float)accS[i][j][r]);
            float p = expf(l - mF[ri]) / sF[ri];
            q = (int)rintf(__fmul_rn(p, 127.0f));
          }
          Ps[wm * 32 + i * 16 + quad * 4 + r][wn * 32 + j * 16 + col] = (int8_t)q;
        }
      }
    }
    __syncthreads();
    v4i a2[2], b2[8];
    #pragma unroll
    for (int i = 0; i < 2; ++i)
      a2[i] = *(const v4i*)&Ps[wm * 32 + i * 16 + col][quad * 16];
    #pragma unroll
    for (int dt = 0; dt < 8; ++dt)
      b2[dt] = *(const v4i*)(KVs + (wn * 128 + dt * 16 + col) * 64 + quad * 16);
    #pragma unroll
    for (int i = 0; i < 2; ++i)
      #pragma unroll
      for (int dt = 0; dt < 8; ++dt)
        pv[i][dt] = __builtin_amdgcn_mfma_i32_16x16x64_i8(a2[i], b2[dt], pv[i][dt], 0, 0, 0);
  }

  #pragma unroll
  for (int i = 0; i < 2; ++i) {
    #pragma unroll
    for (int r = 0; r < 4; ++r) {
      const int t = t0 + wm * 32 + i * 16 + quad * 4 + r;
      #pragma unroll
      for (int dt = 0; dt < 8; ++dt) {
        const int d = wn * 128 + dt * 16 + col;
        float y = rintf(__fmul_rn(apv, (float)pv[i][dt][r]));
        y = fminf(fmaxf(y, -128.0f), 127.0f);
        attn8[(size_t)t * E_ + h * D_ + d] = (int8_t)(int)y;
      }
    }
  }
}

// =============== fallback dot4 kernels (small-ws path) ======================
__global__ __launch_bounds__(256) void qkv_gemm_fb(
    const int* __restrict__ xp,
    const int* __restrict__ Wqp, const int* __restrict__ bq,
    const int* __restrict__ Wkp, const int* __restrict__ bk,
    const int* __restrict__ Wvp, const int* __restrict__ bv,
    const float* __restrict__ alpq, const float* __restrict__ betq,
    const float* __restrict__ alpk, const float* __restrict__ betk,
    const float* __restrict__ alpv, const float* __restrict__ betv,
    const float* __restrict__ sinT, const float* __restrict__ cosT,
    int8_t* __restrict__ Q8, int8_t* __restrict__ K8, int8_t* __restrict__ VT)
{
  const int mode = blockIdx.z;
  const int* __restrict__ Wp = (mode == 0) ? Wqp : (mode == 1 ? Wkp : Wvp);
  const int* __restrict__ bs = (mode == 0) ? bq  : (mode == 1 ? bk  : bv);
  const float alpha = (mode == 0) ? alpq[0] : (mode == 1 ? alpk[0] : alpv[0]);
  const float beta  = (mode == 0) ? betq[0] : (mode == 1 ? betk[0] : betv[0]);

  __shared__ int As[64 * 17];
  __shared__ int Bs[64 * 17];
  const int tid = threadIdx.x;
  const int tx = tid & 15, ty = tid >> 4;
  const int t0 = blockIdx.x * 64, o0 = blockIdx.y * 64;
  const int lrow = tid >> 2, lc = tid & 3;
  int acc[4][4] = {};

  for (int e0 = 0; e0 < E_; e0 += 64) {
    const int* xr = xp + (size_t)(t0 + lrow) * E_ + e0 + lc * 16;
    const int* wr = Wp + (size_t)(o0 + lrow) * E_ + e0 + lc * 16;
    int a4[4], b4[4];
    #pragma unroll
    for (int u = 0; u < 4; ++u) a4[u] = pack4i(((const int4*)xr)[u]);
    #pragma unroll
    for (int u = 0; u < 4; ++u) b4[u] = pack4i(((const int4*)wr)[u]);
    __syncthreads();
    int* ap = &As[lrow * 17 + lc * 4];
    ap[0] = a4[0]; ap[1] = a4[1]; ap[2] = a4[2]; ap[3] = a4[3];
    int* bp = &Bs[lrow * 17 + lc * 4];
    bp[0] = b4[0]; bp[1] = b4[1]; bp[2] = b4[2]; bp[3] = b4[3];
    __syncthreads();
    #pragma unroll
    for (int kk = 0; kk < 16; ++kk) {
      int a[4], b[4];
      #pragma unroll
      for (int i = 0; i < 4; ++i) a[i] = As[(ty * 4 + i) * 17 + kk];
      #pragma unroll
      for (int j = 0; j < 4; ++j) b[j] = Bs[(tx * 4 + j) * 17 + kk];
      #pragma unroll
      for (int i = 0; i < 4; ++i)
        #pragma unroll
        for (int j = 0; j < 4; ++j)
          acc[i][j] = dot4(a[i], b[j], acc[i][j]);
    }
  }

  const int ob = o0 + tx * 4;
  const int h  = ob >> 8;
  const int dd = ob & 255;
  #pragma unroll
  for (int i = 0; i < 4; ++i) {
    const int t = t0 + ty * 4 + i;
    float y[4];
    #pragma unroll
    for (int j = 0; j < 4; ++j) {
      float v = __fadd_rn(__fmul_rn(alpha, (float)acc[i][j]),
                          __fmul_rn(beta, (float)bs[ob + j]));
      v = rintf(v);
      y[j] = fminf(fmaxf(v, -128.0f), 127.0f);
    }
    int q0, q1, q2, q3;
    if (mode < 2 && dd < 64) {
      const int j0 = dd >> 1;
      const float s0 = sinT[t * NF + j0],     c0 = cosT[t * NF + j0];
      const float s1 = sinT[t * NF + j0 + 1], c1 = cosT[t * NF + j0 + 1];
      float r0 = __fadd_rn(__fmul_rn(y[0], c0), __fmul_rn(-y[1], s0));
      float r1 = __fadd_rn(__fmul_rn(y[1], c0), __fmul_rn( y[0], s0));
      float r2 = __fadd_rn(__fmul_rn(y[2], c1), __fmul_rn(-y[3], s1));
      float r3 = __fadd_rn(__fmul_rn(y[3], c1), __fmul_rn( y[2], s1));
      q0 = (int)fminf(fmaxf(truncf(r0), -128.0f), 127.0f);
      q1 = (int)fminf(fmaxf(truncf(r1), -128.0f), 127.0f);
      q2 = (int)fminf(fmaxf(truncf(r2), -128.0f), 127.0f);
      q3 = (int)fminf(fmaxf(truncf(r3), -128.0f), 127.0f);
    } else {
      q0 = (int)y[0]; q1 = (int)y[1]; q2 = (int)y[2]; q3 = (int)y[3];
    }
    if (mode == 2) {
      VT[((size_t)h * 256 + dd + 0) * T_ + t] = (int8_t)q0;
      VT[((size_t)h * 256 + dd + 1) * T_ + t] = (int8_t)q1;
      VT[((size_t)h * 256 + dd + 2) * T_ + t] = (int8_t)q2;
      VT[((size_t)h * 256 + dd + 3) * T_ + t] = (int8_t)q3;
    } else {
      int8_t* dst = (mode == 0) ? Q8 : K8;
      int packed = (q0 & 255) | ((q1 & 255) << 8) | ((q2 & 255) << 16) | ((q3 & 255) << 24);
      *(int*)(dst + ((size_t)h * T_ + t) * D_ + dd) = packed;
    }
  }
}

__global__ __launch_bounds__(256) void out_gemm_fb(
    const int8_t* __restrict__ xa, const int* __restrict__ Wop,
    const float* __restrict__ b_out, const float* __restrict__ p_aout,
    float* __restrict__ out)
{
  __shared__ int As[64 * 17];
  __shared__ int Bs[64 * 17];
  const float alpha = p_aout[0];
  const int tid = threadIdx.x;
  const int tx = tid & 15, ty = tid >> 4;
  const int t0 = blockIdx.x * 64, o0 = blockIdx.y * 64;
  const int lrow = tid >> 2, lc = tid & 3;
  int acc[4][4] = {};

  for (int e0 = 0; e0 < E_; e0 += 64) {
    int4 av4 = *(const int4*)(xa + (size_t)(t0 + lrow) * E_ + e0 + lc * 16);
    const int* wr = Wop + (size_t)(o0 + lrow) * E_ + e0 + lc * 16;
    int b4[4];
    #pragma unroll
    for (int u = 0; u < 4; ++u) b4[u] = pack4i(((const int4*)wr)[u]);
    __syncthreads();
    int* ap = &As[lrow * 17 + lc * 4];
    ap[0] = av4.x; ap[1] = av4.y; ap[2] = av4.z; ap[3] = av4.w;
    int* bp = &Bs[lrow * 17 + lc * 4];
    bp[0] = b4[0]; bp[1] = b4[1]; bp[2] = b4[2]; bp[3] = b4[3];
    __syncthreads();
    #pragma unroll
    for (int kk = 0; kk < 16; ++kk) {
      int a[4], b[4];
      #pragma unroll
      for (int i = 0; i < 4; ++i) a[i] = As[(ty * 4 + i) * 17 + kk];
      #pragma unroll
      for (int j = 0; j < 4; ++j) b[j] = Bs[(tx * 4 + j) * 17 + kk];
      #pragma unroll
      for (int i = 0; i < 4; ++i)
        #pragma unroll
        for (int j = 0; j < 4; ++j)
          acc[i][j] = dot4(a[i], b[j], acc[i][j]);
    }
  }
  #pragma unroll
  for (int i = 0; i < 4; ++i) {
    const int t = t0 + ty * 4 + i;
    const int ob = o0 + tx * 4;
    #pragma unroll
    for (int j = 0; j < 4; ++j) {
      out[(size_t)t * E_ + ob + j] =
          __fadd_rn(__fmul_rn(alpha, (float)acc[i][j]), b_out[ob + j]);
    }
  }
}

extern "C" void kernel_launch(void* const* d_in, const int* in_sizes, int n_in,
                              void* d_out, int out_size, void* d_ws, size_t ws_size,
                              hipStream_t stream) {
  const int* hs   = (const int*)d_in[0];
  const int* Wq   = (const int*)d_in[1];
  const int* bq   = (const int*)d_in[2];
  const int* Wk   = (const int*)d_in[3];
  const int* bk   = (const int*)d_in[4];
  const int* Wv   = (const int*)d_in[5];
  const int* bv   = (const int*)d_in[6];
  const int* Wo   = (const int*)d_in[7];
  const float* b_out = (const float*)d_in[8];
  const float* aq   = (const float*)d_in[9];
  const float* btq  = (const float*)d_in[10];
  const float* ak   = (const float*)d_in[11];
  const float* btk  = (const float*)d_in[12];
  const float* av   = (const float*)d_in[13];
  const float* btv  = (const float*)d_in[14];
  const float* aqk  = (const float*)d_in[15];
  const float* apv  = (const float*)d_in[16];
  const float* aout = (const float*)d_in[17];

  const size_t SEG = (size_t)H_ * T_ * D_;          // 8 MB
  char* ws = (char*)d_ws;
  int8_t* Q8    = (int8_t*)ws;
  int8_t* K8    = Q8 + SEG;
  int8_t* VT    = K8 + SEG;                          // transposed V [h][d][t]
  int8_t* attn8 = VT + SEG;                          // aliased with x8
  int8_t* x8    = attn8;
  float*  sinT  = (float*)(ws + 4 * SEG);
  float*  cosT  = sinT + T_ * NF;
  int8_t* Wq8   = (int8_t*)(cosT + T_ * NF);
  int8_t* Wk8   = Wq8 + (size_t)E_ * E_;
  int8_t* Wv8   = Wk8 + (size_t)E_ * E_;
  int8_t* Wo8   = Wv8 + (size_t)E_ * E_;
  const size_t NEED = 4 * SEG + 2 * (size_t)T_ * NF * 4 + 4 * (size_t)E_ * E_;
  const bool big = (ws_size >= NEED);

  sincos_kernel<<<(T_ * NF) / 256, 256, 0, stream>>>(sinT, cosT);

  if (big) {
    repack5_kernel<<<dim3((E_ * E_ / 16) / 256, 5), 256, 0, stream>>>(
        hs, Wq, Wk, Wv, Wo, x8, Wq8, Wk8, Wv8, Wo8);
    qkv_gemm_mfma<<<dim3(T_ / 128, E_ / 128, 3), 256, 0, stream>>>(
        x8, Wq8, bq, Wk8, bk, Wv8, bv, aq, btq, ak, btk, av, btv,
        sinT, cosT, Q8, K8, VT);

    // --- split-s attention. Scratch aliases dead regions:
    //   P1 (16.78 MB)       <- Wq8   (dead after qkv)
    //   P0 (33.55 MB)       <- Wk8+Wv8 (dead after qkv)
    //   mPart/sPart         <- attn8 region (x8 dead; overwritten by combine)
    int*   P1g   = (int*)Wq8;
    int*   P0g   = (int*)Wk8;
    float* mPart = (float*)attn8;                    // 1 MB
    float* sPart = mPart + (size_t)H_ * 32 * 64 * 8; // 1 MB

    attn_ms_chunk<<<dim3(8, 32, H_), 256, 0, stream>>>(Q8, K8, aqk, mPart, sPart);
    attn_pv_chunk<<<dim3(2, 32, H_), 256, 0, stream>>>(
        Q8, K8, VT, aqk, mPart, sPart, P0g, P1g);
    attn_pv_combine<<<(H_ * 32 * 64 * 64) / 256, 256, 0, stream>>>(
        P0g, P1g, apv, attn8);

    out_gemm_mfma<<<dim3(T_ / 128, E_ / 128), 256, 0, stream>>>(
        attn8, Wo8, b_out, aout, (float*)d_out);
  } else {
    qkv_gemm_fb<<<dim3(T_ / 64, E_ / 64, 3), 256, 0, stream>>>(
        hs, Wq, bq, Wk, bk, Wv, bv, aq, btq, ak, btk, av, btv,
        sinT, cosT, Q8, K8, VT);
    attn_mfma<<<dim3(T_ / 64, H_), 256, 0, stream>>>(Q8, K8, VT, aqk, apv, attn8);
    out_gemm_fb<<<dim3(T_ / 64, E_ / 64), 256, 0, stream>>>(
        attn8, Wo, b_out, aout, (float*)d_out);
  }
}

// Round 6
// 637.178 us; speedup vs baseline: 1.1581x; 1.1581x over previous
//
#include <hip/hip_runtime.h>
#include <cstdint>
#include <cmath>

#define T_ 2048
#define E_ 4096
#define H_ 16
#define D_ 256
#define NF 32   // rotary freq count (R/2)

typedef int v4i  __attribute__((ext_vector_type(4)));

__device__ __forceinline__ int dot4(int a, int b, int c) {
#if __has_builtin(__builtin_amdgcn_sdot4)
  return __builtin_amdgcn_sdot4(a, b, c, false);
#else
  c += ((a << 24) >> 24) * ((b << 24) >> 24);
  c += ((a << 16) >> 24) * ((b << 16) >> 24);
  c += ((a <<  8) >> 24) * ((b <<  8) >> 24);
  c += (a >> 24) * (b >> 24);
  return c;
#endif
}

__device__ __forceinline__ int pack4i(int4 v) {
  return (v.x & 255) | ((v.y & 255) << 8) | ((v.z & 255) << 16) | (v.w << 24);
}

#define GLD_LDS16(g, l)                                                        \
  __builtin_amdgcn_global_load_lds(                                            \
      (const __attribute__((address_space(1))) void*)(g),                      \
      (__attribute__((address_space(3))) void*)(l), 16, 0, 0)

// ---------------- sin/cos table (double-precision, cast to f32) -------------
__global__ void sincos_kernel(float* __restrict__ sinT, float* __restrict__ cosT) {
  int idx = blockIdx.x * 256 + threadIdx.x;   // t*32 + j
  int t = idx >> 5, j = idx & 31;
  float invf = (float)exp(-(double)j * (log(10000.0) / 32.0));
  float ang = (float)t * invf;                // f32 product, matches reference
  sinT[idx] = (float)sin((double)ang);
  cosT[idx] = (float)cos((double)ang);
}

// ---- all 5 repacks (x + 4 weights) in one dispatch: grid (E*E/16/256, 5) ---
__global__ __launch_bounds__(256) void repack5_kernel(
    const int* __restrict__ sx, const int* __restrict__ s1,
    const int* __restrict__ s2, const int* __restrict__ s3,
    const int* __restrict__ s4,
    int8_t* __restrict__ dx, int8_t* __restrict__ d1,
    int8_t* __restrict__ d2, int8_t* __restrict__ d3,
    int8_t* __restrict__ d4) {
  const int w = blockIdx.y;
  if (w == 0 && blockIdx.x >= (T_ * E_ / 16) / 256) return;  // x is 1/2 size
  const int* __restrict__ src =
      (w == 0) ? sx : (w == 1 ? s1 : (w == 2 ? s2 : (w == 3 ? s3 : s4)));
  int8_t* __restrict__ dst =
      (w == 0) ? dx : (w == 1 ? d1 : (w == 2 ? d2 : (w == 3 ? d3 : d4)));
  size_t i = (size_t)blockIdx.x * 256 + threadIdx.x;
  const int4* s = (const int4*)src + i * 4;
  int4 a = s[0], b = s[1], c = s[2], d = s[3];
  int4 o;
  o.x = pack4i(a); o.y = pack4i(b); o.z = pack4i(c); o.w = pack4i(d);
  ((int4*)dst)[i] = o;
}

// =================== MFMA int8 GEMM: QKV projection + fused RoPE ============
// r2-verified structure: grid (T/128, E/128, 3), block 256, wave tile 64x64,
// triple-buffered LDS (48 KB -> 3 blocks/CU), counted vmcnt(4), XOR swizzle
// with pre-swizzled global source. mode 2 (V) writes transposed VT[h][d][t].
// RoPE (d<64) fused into the epilogue via __shfl_xor pair exchange.
__global__ __launch_bounds__(256, 3) void qkv_gemm_mfma(
    const int8_t* __restrict__ x8,
    const int8_t* __restrict__ Wq8, const int* __restrict__ bq,
    const int8_t* __restrict__ Wk8, const int* __restrict__ bk,
    const int8_t* __restrict__ Wv8, const int* __restrict__ bv,
    const float* __restrict__ alpq, const float* __restrict__ betq,
    const float* __restrict__ alpk, const float* __restrict__ betk,
    const float* __restrict__ alpv, const float* __restrict__ betv,
    const float* __restrict__ sinT, const float* __restrict__ cosT,
    int8_t* __restrict__ Q8, int8_t* __restrict__ K8, int8_t* __restrict__ VT)
{
  const int mode = blockIdx.z;
  const int8_t* __restrict__ W = (mode == 0) ? Wq8 : (mode == 1 ? Wk8 : Wv8);
  const int* __restrict__ bs   = (mode == 0) ? bq  : (mode == 1 ? bk  : bv);
  const float alpha = (mode == 0) ? alpq[0] : (mode == 1 ? alpk[0] : alpv[0]);
  const float beta  = (mode == 0) ? betq[0] : (mode == 1 ? betk[0] : betv[0]);

  __shared__ int8_t As[3][8192];
  __shared__ int8_t Bs[3][8192];

  const int tid  = threadIdx.x;
  const int wave = tid >> 6, lane = tid & 63;
  const int wm = wave >> 1, wn = wave & 1;
  const int t0 = blockIdx.x * 128, o0 = blockIdx.y * 128;

  const int srow = lane >> 2;
  const int scol = ((lane & 3) ^ ((lane >> 3) & 3)) * 16;  // pre-swizzled src
  const int col  = lane & 15;
  const int quad = lane >> 4;

  v4i acc[4][4] = {};

  const int8_t* gA0 = x8 + (size_t)(t0 + wave * 32 + srow) * E_ + scol;
  const int8_t* gB0 = W  + (size_t)(o0 + wave * 32 + srow) * E_ + scol;

#define STAGE_QKV(bufi, kt) do {                                               \
    const int e0_ = (kt) * 64;                                                 \
    GLD_LDS16(gA0 + e0_,           As[bufi] + wave * 2048);                    \
    GLD_LDS16(gA0 + e0_ + 16 * E_, As[bufi] + wave * 2048 + 1024);             \
    GLD_LDS16(gB0 + e0_,           Bs[bufi] + wave * 2048);                    \
    GLD_LDS16(gB0 + e0_ + 16 * E_, Bs[bufi] + wave * 2048 + 1024);             \
  } while (0)

  int aoff[4], boff[4];
  #pragma unroll
  for (int i = 0; i < 4; ++i) {
    const int ra = wm * 64 + i * 16 + col;
    aoff[i] = ra * 64 + ((quad ^ ((ra >> 1) & 3)) * 16);
    const int rb = wn * 64 + i * 16 + col;
    boff[i] = rb * 64 + ((quad ^ ((rb >> 1) & 3)) * 16);
  }

  STAGE_QKV(0, 0);
  STAGE_QKV(1, 1);

  int cur = 0;
  for (int kt = 0; kt < 64; ++kt) {
    if (kt == 63) asm volatile("s_waitcnt vmcnt(0)" ::: "memory");
    else          asm volatile("s_waitcnt vmcnt(4)" ::: "memory");
    __builtin_amdgcn_s_barrier();
    if (kt < 62) {
      int nb = cur + 2; if (nb >= 3) nb -= 3;
      STAGE_QKV(nb, kt + 2);
    }
    v4i a[4], b[4];
    #pragma unroll
    for (int i = 0; i < 4; ++i)
      a[i] = *(const v4i*)(As[cur] + aoff[i]);
    #pragma unroll
    for (int j = 0; j < 4; ++j)
      b[j] = *(const v4i*)(Bs[cur] + boff[j]);
    __builtin_amdgcn_s_setprio(1);
    #pragma unroll
    for (int i = 0; i < 4; ++i)
      #pragma unroll
      for (int j = 0; j < 4; ++j)
        acc[i][j] = __builtin_amdgcn_mfma_i32_16x16x64_i8(a[i], b[j], acc[i][j], 0, 0, 0);
    __builtin_amdgcn_s_setprio(0);
    cur = (cur == 2) ? 0 : cur + 1;
  }
#undef STAGE_QKV

  int8_t* __restrict__ dst = (mode == 0) ? Q8 : (mode == 1 ? K8 : VT);
  // rope applies to dd<64 of each head: wave-uniform (o0%256==0 && wn==0)
  const bool ropeWave = (mode < 2) && ((o0 & 128) == 0) && (wn == 0);
  #pragma unroll
  for (int j = 0; j < 4; ++j) {
    const int o  = o0 + wn * 64 + j * 16 + col;
    const int h  = o >> 8;
    const int dd = o & 255;
    const float bb = (float)bs[o];
    const int jj = dd >> 1;
    #pragma unroll
    for (int i = 0; i < 4; ++i) {
      const int tb = t0 + wm * 64 + i * 16 + quad * 4;
      int qb[4];
      #pragma unroll
      for (int r = 0; r < 4; ++r) {
        float v = __fadd_rn(__fmul_rn(alpha, (float)acc[i][j][r]),
                            __fmul_rn(beta, bb));
        v = rintf(v);
        v = fminf(fmaxf(v, -128.0f), 127.0f);
        qb[r] = (int)v;
      }
      if (ropeWave) {
        // lanes col / col^1 hold dd / dd^1 of the same row: exchange via shfl
        #pragma unroll
        for (int r = 0; r < 4; ++r) {
          float y  = (float)qb[r];
          float yo = __shfl_xor(y, 1);
          const int t = tb + r;
          const float s = sinT[t * NF + jj];
          const float c = cosT[t * NF + jj];
          float rv = ((col & 1) == 0)
              ? __fadd_rn(__fmul_rn(y, c), __fmul_rn(-yo, s))
              : __fadd_rn(__fmul_rn(y, c), __fmul_rn(yo, s));
          qb[r] = (int)fminf(fmaxf(truncf(rv), -128.0f), 127.0f);
        }
      }
      if (mode == 2) {
        int packed = (qb[0] & 255) | ((qb[1] & 255) << 8) |
                     ((qb[2] & 255) << 16) | ((qb[3] & 255) << 24);
        *(int*)(dst + ((size_t)h * 256 + dd) * T_ + tb) = packed;
      } else {
        #pragma unroll
        for (int r = 0; r < 4; ++r)
          dst[((size_t)h * T_ + tb + r) * D_ + dd] = (int8_t)qb[r];
      }
    }
  }
}

// =================== MFMA int8 GEMM: output projection =======================
// r2-verified config: grid (T/128, E/128), block 256, triple-buffer, vmcnt(4).
__global__ __launch_bounds__(256, 3) void out_gemm_mfma(
    const int8_t* __restrict__ xa, const int8_t* __restrict__ Wo8,
    const float* __restrict__ b_out, const float* __restrict__ p_aout,
    float* __restrict__ out)
{
  const float alpha = p_aout[0];
  __shared__ int8_t As[3][8192];
  __shared__ int8_t Bs[3][8192];

  const int tid  = threadIdx.x;
  const int wave = tid >> 6, lane = tid & 63;
  const int wm = wave >> 1, wn = wave & 1;
  const int t0 = blockIdx.x * 128, o0 = blockIdx.y * 128;
  const int srow = lane >> 2;
  const int scol = ((lane & 3) ^ ((lane >> 3) & 3)) * 16;
  const int col = lane & 15, quad = lane >> 4;

  v4i acc[4][4] = {};
  const int8_t* gA0 = xa  + (size_t)(t0 + wave * 32 + srow) * E_ + scol;
  const int8_t* gB0 = Wo8 + (size_t)(o0 + wave * 32 + srow) * E_ + scol;

#define STAGE_OUT(bufi, kt) do {                                               \
    const int e0_ = (kt) * 64;                                                 \
    GLD_LDS16(gA0 + e0_,           As[bufi] + wave * 2048);                    \
    GLD_LDS16(gA0 + e0_ + 16 * E_, As[bufi] + wave * 2048 + 1024);             \
    GLD_LDS16(gB0 + e0_,           Bs[bufi] + wave * 2048);                    \
    GLD_LDS16(gB0 + e0_ + 16 * E_, Bs[bufi] + wave * 2048 + 1024);             \
  } while (0)

  int aoff[4], boff[4];
  #pragma unroll
  for (int i = 0; i < 4; ++i) {
    const int ra = wm * 64 + i * 16 + col;
    aoff[i] = ra * 64 + ((quad ^ ((ra >> 1) & 3)) * 16);
    const int rb = wn * 64 + i * 16 + col;
    boff[i] = rb * 64 + ((quad ^ ((rb >> 1) & 3)) * 16);
  }

  STAGE_OUT(0, 0);
  STAGE_OUT(1, 1);

  int cur = 0;
  for (int kt = 0; kt < 64; ++kt) {
    if (kt == 63) asm volatile("s_waitcnt vmcnt(0)" ::: "memory");
    else          asm volatile("s_waitcnt vmcnt(4)" ::: "memory");
    __builtin_amdgcn_s_barrier();
    if (kt < 62) {
      int nb = cur + 2; if (nb >= 3) nb -= 3;
      STAGE_OUT(nb, kt + 2);
    }
    v4i a[4], b[4];
    #pragma unroll
    for (int i = 0; i < 4; ++i)
      a[i] = *(const v4i*)(As[cur] + aoff[i]);
    #pragma unroll
    for (int j = 0; j < 4; ++j)
      b[j] = *(const v4i*)(Bs[cur] + boff[j]);
    __builtin_amdgcn_s_setprio(1);
    #pragma unroll
    for (int i = 0; i < 4; ++i)
      #pragma unroll
      for (int j = 0; j < 4; ++j)
        acc[i][j] = __builtin_amdgcn_mfma_i32_16x16x64_i8(a[i], b[j], acc[i][j], 0, 0, 0);
    __builtin_amdgcn_s_setprio(0);
    cur = (cur == 2) ? 0 : cur + 1;
  }
#undef STAGE_OUT

  #pragma unroll
  for (int j = 0; j < 4; ++j) {
    const int o = o0 + wn * 64 + j * 16 + col;
    const float bb = b_out[o];
    #pragma unroll
    for (int i = 0; i < 4; ++i) {
      #pragma unroll
      for (int r = 0; r < 4; ++r) {
        const int t = t0 + wm * 64 + i * 16 + quad * 4 + r;
        out[(size_t)t * E_ + o] = __fadd_rn(__fmul_rn(alpha, (float)acc[i][j][r]), bb);
      }
    }
  }
}

// =================== split-s attention, kernel A: m/s partials ==============
// grid (8 chunks, 32 qtiles, 16 heads), block 256. chunk = 4 K-tiles of 64.
// K double-buffered, XOR-swizzled Q/K, branchless online softmax with native
// __expf (v_exp_f32) -- exactly equivalent to the branchy form since
// __expf(0)==1.0f and fma with 1.0 is an exact add.
__global__ __launch_bounds__(256) void attn_ms_chunk(
    const int8_t* __restrict__ Q8, const int8_t* __restrict__ K8,
    const float* __restrict__ p_aqk,
    float* __restrict__ mPart, float* __restrict__ sPart)
{
  const int ch = blockIdx.x;
  const int qi = blockIdx.y;
  const int h  = blockIdx.z;
  if ((ch << 2) > qi) return;               // chunk beyond causal diagonal

  __shared__ int8_t Qs[4 * 4096];           // 16 KB, swizzled
  __shared__ int8_t Ks[2][16384];           // K double-buffer, swizzled
  __shared__ float  mred[64][2];
  __shared__ float  sred[64][2];

  const int t0  = qi * 64;
  const int tid = threadIdx.x;
  const int wave = tid >> 6, lane = tid & 63;
  const int wm = wave >> 1, wn = wave & 1;
  const int col = lane & 15, quad = lane >> 4;
  const int srow = lane >> 2;
  const int scol = ((lane & 3) ^ ((lane >> 3) & 3)) * 16;  // pre-swizzled src
  const float aqk = p_aqk[0] * 0.0625f;

  const int it0 = ch * 4;
  const int it1 = (it0 + 3 < qi) ? (it0 + 3) : qi;

  // stage Q + first K tile; drain; barrier
  {
    const int8_t* g = Q8 + ((size_t)h * T_ + t0 + wave * 16 + srow) * D_ + scol;
    #pragma unroll
    for (int c = 0; c < 4; ++c)
      GLD_LDS16(g + c * 64, Qs + c * 4096 + wave * 1024);
    const int8_t* gk = K8 + ((size_t)h * T_ + it0 * 64 + wave * 16 + srow) * D_ + scol;
    #pragma unroll
    for (int c = 0; c < 4; ++c)
      GLD_LDS16(gk + c * 64, Ks[0] + c * 4096 + wave * 1024);
  }
  asm volatile("s_waitcnt vmcnt(0)" ::: "memory");
  __builtin_amdgcn_s_barrier();

  int qoff[2], koff[2];
  #pragma unroll
  for (int i = 0; i < 2; ++i) {
    const int ra = wm * 32 + i * 16 + col;
    qoff[i] = ra * 64 + ((quad ^ ((ra >> 1) & 3)) * 16);
    const int rb = wn * 32 + i * 16 + col;
    koff[i] = rb * 64 + ((quad ^ ((rb >> 1) & 3)) * 16);
  }

  float m[8], sm[8];
  #pragma unroll
  for (int u = 0; u < 8; ++u) { m[u] = -INFINITY; sm[u] = 0.0f; }

  int cur = 0;
  for (int it = it0; it <= it1; ++it) {
    const int s0 = it * 64;
    if (it < it1) {                         // prefetch next K tile
      const int8_t* g = K8 + ((size_t)h * T_ + (it + 1) * 64 + wave * 16 + srow) * D_ + scol;
      #pragma unroll
      for (int c = 0; c < 4; ++c)
        GLD_LDS16(g + c * 64, Ks[cur ^ 1] + c * 4096 + wave * 1024);
    }
    v4i accS[2][2] = {};
    #pragma unroll
    for (int c = 0; c < 4; ++c) {
      v4i a[2], b[2];
      #pragma unroll
      for (int i = 0; i < 2; ++i)
        a[i] = *(const v4i*)(Qs + c * 4096 + qoff[i]);
      #pragma unroll
      for (int j = 0; j < 2; ++j)
        b[j] = *(const v4i*)(Ks[cur] + c * 4096 + koff[j]);
      #pragma unroll
      for (int i = 0; i < 2; ++i)
        #pragma unroll
        for (int j = 0; j < 2; ++j)
          accS[i][j] = __builtin_amdgcn_mfma_i32_16x16x64_i8(a[i], b[j], accS[i][j], 0, 0, 0);
    }
    const bool diag = (s0 == t0);
    #pragma unroll
    for (int i = 0; i < 2; ++i) {
      #pragma unroll
      for (int r = 0; r < 4; ++r) {
        const int ri = i * 4 + r;
        const int qrow = t0 + wm * 32 + i * 16 + quad * 4 + r;
        #pragma unroll
        for (int j = 0; j < 2; ++j) {
          const int s = s0 + wn * 32 + j * 16 + col;
          if (!diag || s <= qrow) {
            float l = __fmul_rn(aqk, (float)accS[i][j][r]);
            float nm = fmaxf(m[ri], l);
            float e1 = __expf(m[ri] - nm);      // ==1.0f when m is the max
            float e2 = __expf(l - nm);          // ==1.0f when l is the max
            sm[ri] = sm[ri] * e1 + e2;
            m[ri] = nm;
          }
        }
      }
    }
    // prefetch complete + all reads of Ks[cur] done (they precede this point)
    asm volatile("s_waitcnt vmcnt(0)" ::: "memory");
    __builtin_amdgcn_s_barrier();
    cur ^= 1;
  }

  // reduce over the 16 col-lanes (NaN-guarded for fully-masked lanes)
  #pragma unroll
  for (int u = 0; u < 8; ++u) {
    #pragma unroll
    for (int off = 1; off < 16; off <<= 1) {
      float om = __shfl_xor(m[u], off);
      float os = __shfl_xor(sm[u], off);
      float mm = fmaxf(m[u], om);
      float e1 = (m[u] == mm) ? 1.0f : __expf(m[u] - mm);
      float e2 = (om   == mm) ? 1.0f : __expf(om - mm);
      sm[u] = sm[u] * e1 + os * e2;
      m[u] = mm;
    }
  }
  __syncthreads();
  if (col == 0) {
    #pragma unroll
    for (int u = 0; u < 8; ++u) {
      int row = wm * 32 + (u >> 2) * 16 + quad * 4 + (u & 3);
      mred[row][wn] = m[u];
      sred[row][wn] = sm[u];
    }
  }
  __syncthreads();
  if (col == 0 && wn == 0) {
    #pragma unroll
    for (int u = 0; u < 8; ++u) {
      int row = wm * 32 + (u >> 2) * 16 + quad * 4 + (u & 3);
      float m0 = mred[row][0], m1 = mred[row][1];
      float sa = sred[row][0], sb = sred[row][1];
      float mm = fmaxf(m0, m1);
      float e0 = (m0 == mm) ? 1.0f : __expf(m0 - mm);
      float e1 = (m1 == mm) ? 1.0f : __expf(m1 - mm);
      size_t base = (((size_t)h * 32 + qi) * 64 + row) * 8 + ch;
      mPart[base] = mm;
      sPart[base] = __fadd_rn(__fmul_rn(sa, e0), __fmul_rn(sb, e1));
    }
  }
}

// =================== kernel C: P quantize + PV int32 partials ===============
// grid (2 chunks, 32 qtiles, 16 heads). chunk = 16 K-tiles. heavy-first.
// K double-buffered in LDS, V direct-to-registers, Ps padded, XOR swizzle.
// Softmax uses native __expf and a per-row hoisted reciprocal (8 divides per
// block instead of 16 per thread per iteration).
__global__ __launch_bounds__(256) void attn_pv_chunk(
    const int8_t* __restrict__ Q8, const int8_t* __restrict__ K8,
    const int8_t* __restrict__ VT,
    const float* __restrict__ p_aqk,
    const float* __restrict__ mPart, const float* __restrict__ sPart,
    int* __restrict__ P0, int* __restrict__ P1)
{
  const int cc = blockIdx.x;
  const int qi = 31 - blockIdx.y;             // heavy q-tiles dispatched first
  const int h  = blockIdx.z;
  if (cc == 1 && qi < 16) return;

  __shared__ int8_t Qs[4 * 4096];             // 16 KB, swizzled
  __shared__ int8_t Ks[2][16384];             // 32 KB K double-buffer, swizzled
  __shared__ int8_t Ps[64][80];               // padded: kills 8-way conflict

  const int t0  = qi * 64;
  const int tid = threadIdx.x;
  const int wave = tid >> 6, lane = tid & 63;
  const int wm = wave >> 1, wn = wave & 1;
  const int col = lane & 15, quad = lane >> 4;
  const int srow = lane >> 2;
  const int scol = ((lane & 3) ^ ((lane >> 3) & 3)) * 16;  // pre-swizzled src
  const float aqk = p_aqk[0] * 0.0625f;

  const int it0 = cc * 16;
  const int it1 = (it0 + 15 < qi) ? (it0 + 15) : qi;

  // stage Q + first K tile
  {
    const int8_t* g = Q8 + ((size_t)h * T_ + t0 + wave * 16 + srow) * D_ + scol;
    #pragma unroll
    for (int c = 0; c < 4; ++c)
      GLD_LDS16(g + c * 64, Qs + c * 4096 + wave * 1024);
    const int8_t* gk = K8 + ((size_t)h * T_ + it0 * 64 + wave * 16 + srow) * D_ + scol;
    #pragma unroll
    for (int c = 0; c < 4; ++c)
      GLD_LDS16(gk + c * 64, Ks[0] + c * 4096 + wave * 1024);
  }

  // fold chunk partials into final m/s (identical order to original combine)
  float mF[8], rF[8];
  const int nch = (qi >> 2) + 1;
  #pragma unroll
  for (int u = 0; u < 8; ++u) {
    const int row = wm * 32 + (u >> 2) * 16 + quad * 4 + (u & 3);
    const float* mp = mPart + (((size_t)h * 32 + qi) * 64 + row) * 8;
    const float* sp = sPart + (((size_t)h * 32 + qi) * 64 + row) * 8;
    float m = mp[0], s = sp[0];
    for (int c = 1; c < nch; ++c) {
      float mc = mp[c], sc = sp[c];
      float mm = fmaxf(m, mc);
      float e1 = (m  == mm) ? 1.0f : __expf(m - mm);
      float e2 = (mc == mm) ? 1.0f : __expf(mc - mm);
      s = __fadd_rn(__fmul_rn(s, e1), __fmul_rn(sc, e2));
      m = mm;
    }
    mF[u] = m;
    rF[u] = 1.0f / s;                       // hoisted reciprocal (8 divides)
  }

  asm volatile("s_waitcnt vmcnt(0)" ::: "memory");
  __builtin_amdgcn_s_barrier();               // Q + K(it0) staged everywhere

  int qoff[2], koff[2];
  #pragma unroll
  for (int i = 0; i < 2; ++i) {
    const int ra = wm * 32 + i * 16 + col;
    qoff[i] = ra * 64 + ((quad ^ ((ra >> 1) & 3)) * 16);
    const int rb = wn * 32 + i * 16 + col;
    koff[i] = rb * 64 + ((quad ^ ((rb >> 1) & 3)) * 16);
  }

  v4i pv[2][8] = {};
  int cur = 0;
  for (int it = it0; it <= it1; ++it) {
    const int s0 = it * 64;
    // V fragments -> registers (compiler-managed waits; hidden under QK+softmax)
    v4i vb[8];
    #pragma unroll
    for (int dt = 0; dt < 8; ++dt)
      vb[dt] = *(const v4i*)(VT + ((size_t)h * 256 + wn * 128 + dt * 16 + col) * T_
                             + s0 + quad * 16);
    // prefetch next K tile into the other buffer
    if (it < it1) {
      const int8_t* g = K8 + ((size_t)h * T_ + (it + 1) * 64 + wave * 16 + srow) * D_ + scol;
      #pragma unroll
      for (int c = 0; c < 4; ++c)
        GLD_LDS16(g + c * 64, Ks[cur ^ 1] + c * 4096 + wave * 1024);
    }
    // QK^T from Ks[cur]
    v4i accS[2][2] = {};
    #pragma unroll
    for (int c = 0; c < 4; ++c) {
      v4i a[2], b[2];
      #pragma unroll
      for (int i = 0; i < 2; ++i)
        a[i] = *(const v4i*)(Qs + c * 4096 + qoff[i]);
      #pragma unroll
      for (int j = 0; j < 2; ++j)
        b[j] = *(const v4i*)(Ks[cur] + c * 4096 + koff[j]);
      #pragma unroll
      for (int i = 0; i < 2; ++i)
        #pragma unroll
        for (int j = 0; j < 2; ++j)
          accS[i][j] = __builtin_amdgcn_mfma_i32_16x16x64_i8(a[i], b[j], accS[i][j], 0, 0, 0);
    }
    // softmax -> Ps
    const bool diag = (s0 == t0);
    #pragma unroll
    for (int i = 0; i < 2; ++i) {
      #pragma unroll
      for (int r = 0; r < 4; ++r) {
        const int ri = i * 4 + r;
        const int qrow = t0 + wm * 32 + i * 16 + quad * 4 + r;
        #pragma unroll
        for (int j = 0; j < 2; ++j) {
          const int s = s0 + wn * 32 + j * 16 + col;
          int q = 0;
          if (!diag || s <= qrow) {
            float l = __fmul_rn(aqk, (float)accS[i][j][r]);
            float p = __fmul_rn(__expf(l - mF[ri]), rF[ri]);
            q = (int)rintf(__fmul_rn(p, 127.0f));
          }
          Ps[wm * 32 + i * 16 + quad * 4 + r][wn * 32 + j * 16 + col] = (int8_t)q;
        }
      }
    }
    asm volatile("s_waitcnt lgkmcnt(0)" ::: "memory");  // Ps writes landed
    __builtin_amdgcn_s_barrier();                       // Ps visible; NO vmcnt drain
    // PV: A from Ps (LDS), B from V registers
    v4i a2[2];
    #pragma unroll
    for (int i = 0; i < 2; ++i)
      a2[i] = *(const v4i*)&Ps[wm * 32 + i * 16 + col][quad * 16];
    #pragma unroll
    for (int i = 0; i < 2; ++i)
      #pragma unroll
      for (int dt = 0; dt < 8; ++dt)
        pv[i][dt] = __builtin_amdgcn_mfma_i32_16x16x64_i8(a2[i], vb[dt], pv[i][dt], 0, 0, 0);
    // K prefetch complete; Ps/K reads done before next iter's writes
    asm volatile("s_waitcnt vmcnt(0)" ::: "memory");
    __builtin_amdgcn_s_barrier();
    cur ^= 1;
  }

  // store int32 partial tile
  int* __restrict__ dst = (cc == 0)
      ? P0 + (((size_t)h * 32 + qi) << 14)
      : P1 + (((size_t)h * 16 + (qi - 16)) << 14);
  #pragma unroll
  for (int i = 0; i < 2; ++i) {
    #pragma unroll
    for (int r = 0; r < 4; ++r) {
      const int trow = wm * 32 + i * 16 + quad * 4 + r;
      #pragma unroll
      for (int dt = 0; dt < 8; ++dt) {
        const int d = wn * 128 + dt * 16 + col;
        dst[trow * 256 + d] = pv[i][dt][r];
      }
    }
  }
}

// =================== kernel D: sum partials + quantize -> attn8 =============
__global__ __launch_bounds__(256) void attn_pv_combine(
    const int* __restrict__ P0, const int* __restrict__ P1,
    const float* __restrict__ p_apv, int8_t* __restrict__ attn8)
{
  const float apv = p_apv[0];
  int idx = blockIdx.x * 256 + threadIdx.x;   // h*(32*64*64) + qi*(64*64) + row*64 + d4
  int d4  = idx & 63;
  int row = (idx >> 6) & 63;
  int qi  = (idx >> 12) & 31;
  int h   = idx >> 17;
  size_t off = (((size_t)h * 32 + qi) << 14) + row * 256 + d4 * 4;
  int4 a = *(const int4*)(P0 + off);
  if (qi >= 16) {
    size_t off1 = (((size_t)h * 16 + (qi - 16)) << 14) + row * 256 + d4 * 4;
    int4 b1 = *(const int4*)(P1 + off1);
    a.x += b1.x; a.y += b1.y; a.z += b1.z; a.w += b1.w;
  }
  int q[4];
  int vv[4] = {a.x, a.y, a.z, a.w};
  #pragma unroll
  for (int r = 0; r < 4; ++r) {
    float y = rintf(__fmul_rn(apv, (float)vv[r]));
    y = fminf(fmaxf(y, -128.0f), 127.0f);
    q[r] = (int)y;
  }
  int packed = (q[0] & 255) | ((q[1] & 255) << 8) | ((q[2] & 255) << 16) | ((q[3] & 255) << 24);
  int t = qi * 64 + row;
  *(int*)(attn8 + (size_t)t * E_ + h * D_ + d4 * 4) = packed;
}

// =================== MFMA attention (small-ws fallback path) ================
__global__ __launch_bounds__(256) void attn_mfma(
    const int8_t* __restrict__ Q8, const int8_t* __restrict__ K8,
    const int8_t* __restrict__ VT,
    const float* __restrict__ p_aqk, const float* __restrict__ p_apv,
    int8_t* __restrict__ attn8)
{
  __shared__ int8_t Qs[4 * 4096];
  __shared__ int8_t KVs[16384];
  __shared__ int8_t Ps[64][64];
  __shared__ float  mred[64][2];
  __shared__ float  sred[64][2];

  const int h   = blockIdx.y;
  const int t0  = blockIdx.x * 64;
  const int tid = threadIdx.x;
  const int wave = tid >> 6, lane = tid & 63;
  const int wm = wave >> 1, wn = wave & 1;
  const int col = lane & 15, quad = lane >> 4;
  const int srow = lane >> 2, scol = (lane & 3) * 16;
  const float aqk = p_aqk[0] * 0.0625f;
  const float apv = p_apv[0];

  {
    const int8_t* g = Q8 + ((size_t)h * T_ + t0 + wave * 16 + srow) * D_ + scol;
    #pragma unroll
    for (int c = 0; c < 4; ++c)
      GLD_LDS16(g + c * 64, Qs + c * 4096 + wave * 1024);
  }

  const int nt = t0 / 64 + 1;

  float m[8], sm[8];
  #pragma unroll
  for (int u = 0; u < 8; ++u) { m[u] = -INFINITY; sm[u] = 0.0f; }

  for (int it = 0; it < nt; ++it) {
    const int s0 = it * 64;
    __syncthreads();
    {
      const int8_t* g = K8 + ((size_t)h * T_ + s0 + wave * 16 + srow) * D_ + scol;
      #pragma unroll
      for (int c = 0; c < 4; ++c)
        GLD_LDS16(g + c * 64, KVs + c * 4096 + wave * 1024);
    }
    __syncthreads();
    v4i accS[2][2] = {};
    #pragma unroll
    for (int c = 0; c < 4; ++c) {
      v4i a[2], b[2];
      #pragma unroll
      for (int i = 0; i < 2; ++i)
        a[i] = *(const v4i*)(Qs + c * 4096 + (wm * 32 + i * 16 + col) * 64 + quad * 16);
      #pragma unroll
      for (int j = 0; j < 2; ++j)
        b[j] = *(const v4i*)(KVs + c * 4096 + (wn * 32 + j * 16 + col) * 64 + quad * 16);
      #pragma unroll
      for (int i = 0; i < 2; ++i)
        #pragma unroll
        for (int j = 0; j < 2; ++j)
          accS[i][j] = __builtin_amdgcn_mfma_i32_16x16x64_i8(a[i], b[j], accS[i][j], 0, 0, 0);
    }
    const bool diag = (s0 == t0);
    #pragma unroll
    for (int i = 0; i < 2; ++i) {
      #pragma unroll
      for (int r = 0; r < 4; ++r) {
        const int ri = i * 4 + r;
        const int qrow = t0 + wm * 32 + i * 16 + quad * 4 + r;
        #pragma unroll
        for (int j = 0; j < 2; ++j) {
          const int s = s0 + wn * 32 + j * 16 + col;
          if (!diag || s <= qrow) {
            float l = __fmul_rn(aqk, (float)accS[i][j][r]);
            if (l > m[ri]) { sm[ri] = sm[ri] * expf(m[ri] - l) + 1.0f; m[ri] = l; }
            else           { sm[ri] += expf(l - m[ri]); }
          }
        }
      }
    }
  }

  #pragma unroll
  for (int u = 0; u < 8; ++u) {
    #pragma unroll
    for (int off = 1; off < 16; off <<= 1) {
      float om = __shfl_xor(m[u], off);
      float os = __shfl_xor(sm[u], off);
      float mm = fmaxf(m[u], om);
      float e1 = (m[u] == mm) ? 1.0f : expf(m[u] - mm);
      float e2 = (om   == mm) ? 1.0f : expf(om - mm);
      sm[u] = sm[u] * e1 + os * e2;
      m[u] = mm;
    }
  }
  __syncthreads();
  if (col == 0) {
    #pragma unroll
    for (int u = 0; u < 8; ++u) {
      int row = wm * 32 + (u >> 2) * 16 + quad * 4 + (u & 3);
      mred[row][wn] = m[u];
      sred[row][wn] = sm[u];
    }
  }
  __syncthreads();
  float mF[8], sF[8];
  #pragma unroll
  for (int u = 0; u < 8; ++u) {
    int row = wm * 32 + (u >> 2) * 16 + quad * 4 + (u & 3);
    float m0 = mred[row][0], m1 = mred[row][1];
    float sa = sred[row][0], sb = sred[row][1];
    float mm = fmaxf(m0, m1);
    float e0 = (m0 == mm) ? 1.0f : expf(m0 - mm);
    float e1 = (m1 == mm) ? 1.0f : expf(m1 - mm);
    mF[u] = mm;
    sF[u] = __fadd_rn(__fmul_rn(sa, e0), __fmul_rn(sb, e1));
  }

  v4i pv[2][8] = {};
  for (int it = 0; it < nt; ++it) {
    const int s0 = it * 64;
    __syncthreads();
    {
      const int8_t* g = K8 + ((size_t)h * T_ + s0 + wave * 16 + srow) * D_ + scol;
      #pragma unroll
      for (int c = 0; c < 4; ++c)
        GLD_LDS16(g + c * 64, KVs + c * 4096 + wave * 1024);
    }
    __syncthreads();
    v4i accS[2][2] = {};
    #pragma unroll
    for (int c = 0; c < 4; ++c) {
      v4i a[2], b[2];
      #pragma unroll
      for (int i = 0; i < 2; ++i)
        a[i] = *(const v4i*)(Qs + c * 4096 + (wm * 32 + i * 16 + col) * 64 + quad * 16);
      #pragma unroll
      for (int j = 0; j < 2; ++j)
        b[j] = *(const v4i*)(KVs + c * 4096 + (wn * 32 + j * 16 + col) * 64 + quad * 16);
      #pragma unroll
      for (int i = 0; i < 2; ++i)
        #pragma unroll
        for (int j = 0; j < 2; ++j)
          accS[i][j] = __builtin_amdgcn_mfma_i32_16x16x64_i8(a[i], b[j], accS[i][j], 0, 0, 0);
    }
    __syncthreads();
    {
      #pragma unroll
      for (int c = 0; c < 4; ++c) {
        const int drow = (wave * 4 + c) * 16 + srow;
        GLD_LDS16(VT + ((size_t)h * 256 + drow) * T_ + s0 + scol,
                  KVs + (wave * 4 + c) * 1024);
      }
    }
    const bool diag = (s0 == t0);
    #pragma unroll
    for (int i = 0; i < 2; ++i) {
      #pragma unroll
      for (int r = 0; r < 4; ++r) {
        const int ri = i * 4 + r;
        const int qrow = t0 + wm * 32 + i * 16 + quad * 4 + r;
        #pragma unroll
        for (int j = 0; j < 2; ++j) {
          const int s = s0 + wn * 32 + j * 16 + col;
          int q = 0;
          if (!diag || s <= qrow) {
            float l = __fmul_rn(aqk, (float)accS[i][j][r]);
            float p = expf(l - mF[ri]) / sF[ri];
            q = (int)rintf(__fmul_rn(p, 127.0f));
          }
          Ps[wm * 32 + i * 16 + quad * 4 + r][wn * 32 + j * 16 + col] = (int8_t)q;
        }
      }
    }
    __syncthreads();
    v4i a2[2], b2[8];
    #pragma unroll
    for (int i = 0; i < 2; ++i)
      a2[i] = *(const v4i*)&Ps[wm * 32 + i * 16 + col][quad * 16];
    #pragma unroll
    for (int dt = 0; dt < 8; ++dt)
      b2[dt] = *(const v4i*)(KVs + (wn * 128 + dt * 16 + col) * 64 + quad * 16);
    #pragma unroll
    for (int i = 0; i < 2; ++i)
      #pragma unroll
      for (int dt = 0; dt < 8; ++dt)
        pv[i][dt] = __builtin_amdgcn_mfma_i32_16x16x64_i8(a2[i], b2[dt], pv[i][dt], 0, 0, 0);
  }

  #pragma unroll
  for (int i = 0; i < 2; ++i) {
    #pragma unroll
    for (int r = 0; r < 4; ++r) {
      const int t = t0 + wm * 32 + i * 16 + quad * 4 + r;
      #pragma unroll
      for (int dt = 0; dt < 8; ++dt) {
        const int d = wn * 128 + dt * 16 + col;
        float y = rintf(__fmul_rn(apv, (float)pv[i][dt][r]));
        y = fminf(fmaxf(y, -128.0f), 127.0f);
        attn8[(size_t)t * E_ + h * D_ + d] = (int8_t)(int)y;
      }
    }
  }
}

// =============== fallback dot4 kernels (small-ws path) ======================
__global__ __launch_bounds__(256) void qkv_gemm_fb(
    const int* __restrict__ xp,
    const int* __restrict__ Wqp, const int* __restrict__ bq,
    const int* __restrict__ Wkp, const int* __restrict__ bk,
    const int* __restrict__ Wvp, const int* __restrict__ bv,
    const float* __restrict__ alpq, const float* __restrict__ betq,
    const float* __restrict__ alpk, const float* __restrict__ betk,
    const float* __restrict__ alpv, const float* __restrict__ betv,
    const float* __restrict__ sinT, const float* __restrict__ cosT,
    int8_t* __restrict__ Q8, int8_t* __restrict__ K8, int8_t* __restrict__ VT)
{
  const int mode = blockIdx.z;
  const int* __restrict__ Wp = (mode == 0) ? Wqp : (mode == 1 ? Wkp : Wvp);
  const int* __restrict__ bs = (mode == 0) ? bq  : (mode == 1 ? bk  : bv);
  const float alpha = (mode == 0) ? alpq[0] : (mode == 1 ? alpk[0] : alpv[0]);
  const float beta  = (mode == 0) ? betq[0] : (mode == 1 ? betk[0] : betv[0]);

  __shared__ int As[64 * 17];
  __shared__ int Bs[64 * 17];
  const int tid = threadIdx.x;
  const int tx = tid & 15, ty = tid >> 4;
  const int t0 = blockIdx.x * 64, o0 = blockIdx.y * 64;
  const int lrow = tid >> 2, lc = tid & 3;
  int acc[4][4] = {};

  for (int e0 = 0; e0 < E_; e0 += 64) {
    const int* xr = xp + (size_t)(t0 + lrow) * E_ + e0 + lc * 16;
    const int* wr = Wp + (size_t)(o0 + lrow) * E_ + e0 + lc * 16;
    int a4[4], b4[4];
    #pragma unroll
    for (int u = 0; u < 4; ++u) a4[u] = pack4i(((const int4*)xr)[u]);
    #pragma unroll
    for (int u = 0; u < 4; ++u) b4[u] = pack4i(((const int4*)wr)[u]);
    __syncthreads();
    int* ap = &As[lrow * 17 + lc * 4];
    ap[0] = a4[0]; ap[1] = a4[1]; ap[2] = a4[2]; ap[3] = a4[3];
    int* bp = &Bs[lrow * 17 + lc * 4];
    bp[0] = b4[0]; bp[1] = b4[1]; bp[2] = b4[2]; bp[3] = b4[3];
    __syncthreads();
    #pragma unroll
    for (int kk = 0; kk < 16; ++kk) {
      int a[4], b[4];
      #pragma unroll
      for (int i = 0; i < 4; ++i) a[i] = As[(ty * 4 + i) * 17 + kk];
      #pragma unroll
      for (int j = 0; j < 4; ++j) b[j] = Bs[(tx * 4 + j) * 17 + kk];
      #pragma unroll
      for (int i = 0; i < 4; ++i)
        #pragma unroll
        for (int j = 0; j < 4; ++j)
          acc[i][j] = dot4(a[i], b[j], acc[i][j]);
    }
  }

  const int ob = o0 + tx * 4;
  const int h  = ob >> 8;
  const int dd = ob & 255;
  #pragma unroll
  for (int i = 0; i < 4; ++i) {
    const int t = t0 + ty * 4 + i;
    float y[4];
    #pragma unroll
    for (int j = 0; j < 4; ++j) {
      float v = __fadd_rn(__fmul_rn(alpha, (float)acc[i][j]),
                          __fmul_rn(beta, (float)bs[ob + j]));
      v = rintf(v);
      y[j] = fminf(fmaxf(v, -128.0f), 127.0f);
    }
    int q0, q1, q2, q3;
    if (mode < 2 && dd < 64) {
      const int j0 = dd >> 1;
      const float s0 = sinT[t * NF + j0],     c0 = cosT[t * NF + j0];
      const float s1 = sinT[t * NF + j0 + 1], c1 = cosT[t * NF + j0 + 1];
      float r0 = __fadd_rn(__fmul_rn(y[0], c0), __fmul_rn(-y[1], s0));
      float r1 = __fadd_rn(__fmul_rn(y[1], c0), __fmul_rn( y[0], s0));
      float r2 = __fadd_rn(__fmul_rn(y[2], c1), __fmul_rn(-y[3], s1));
      float r3 = __fadd_rn(__fmul_rn(y[3], c1), __fmul_rn( y[2], s1));
      q0 = (int)fminf(fmaxf(truncf(r0), -128.0f), 127.0f);
      q1 = (int)fminf(fmaxf(truncf(r1), -128.0f), 127.0f);
      q2 = (int)fminf(fmaxf(truncf(r2), -128.0f), 127.0f);
      q3 = (int)fminf(fmaxf(truncf(r3), -128.0f), 127.0f);
    } else {
      q0 = (int)y[0]; q1 = (int)y[1]; q2 = (int)y[2]; q3 = (int)y[3];
    }
    if (mode == 2) {
      VT[((size_t)h * 256 + dd + 0) * T_ + t] = (int8_t)q0;
      VT[((size_t)h * 256 + dd + 1) * T_ + t] = (int8_t)q1;
      VT[((size_t)h * 256 + dd + 2) * T_ + t] = (int8_t)q2;
      VT[((size_t)h * 256 + dd + 3) * T_ + t] = (int8_t)q3;
    } else {
      int8_t* dst = (mode == 0) ? Q8 : K8;
      int packed = (q0 & 255) | ((q1 & 255) << 8) | ((q2 & 255) << 16) | ((q3 & 255) << 24);
      *(int*)(dst + ((size_t)h * T_ + t) * D_ + dd) = packed;
    }
  }
}

__global__ __launch_bounds__(256) void out_gemm_fb(
    const int8_t* __restrict__ xa, const int* __restrict__ Wop,
    const float* __restrict__ b_out, const float* __restrict__ p_aout,
    float* __restrict__ out)
{
  __shared__ int As[64 * 17];
  __shared__ int Bs[64 * 17];
  const float alpha = p_aout[0];
  const int tid = threadIdx.x;
  const int tx = tid & 15, ty = tid >> 4;
  const int t0 = blockIdx.x * 64, o0 = blockIdx.y * 64;
  const int lrow = tid >> 2, lc = tid & 3;
  int acc[4][4] = {};

  for (int e0 = 0; e0 < E_; e0 += 64) {
    int4 av4 = *(const int4*)(xa + (size_t)(t0 + lrow) * E_ + e0 + lc * 16);
    const int* wr = Wop + (size_t)(o0 + lrow) * E_ + e0 + lc * 16;
    int b4[4];
    #pragma unroll
    for (int u = 0; u < 4; ++u) b4[u] = pack4i(((const int4*)wr)[u]);
    __syncthreads();
    int* ap = &As[lrow * 17 + lc * 4];
    ap[0] = av4.x; ap[1] = av4.y; ap[2] = av4.z; ap[3] = av4.w;
    int* bp = &Bs[lrow * 17 + lc * 4];
    bp[0] = b4[0]; bp[1] = b4[1]; bp[2] = b4[2]; bp[3] = b4[3];
    __syncthreads();
    #pragma unroll
    for (int kk = 0; kk < 16; ++kk) {
      int a[4], b[4];
      #pragma unroll
      for (int i = 0; i < 4; ++i) a[i] = As[(ty * 4 + i) * 17 + kk];
      #pragma unroll
      for (int j = 0; j < 4; ++j) b[j] = Bs[(tx * 4 + j) * 17 + kk];
      #pragma unroll
      for (int i = 0; i < 4; ++i)
        #pragma unroll
        for (int j = 0; j < 4; ++j)
          acc[i][j] = dot4(a[i], b[j], acc[i][j]);
    }
  }
  #pragma unroll
  for (int i = 0; i < 4; ++i) {
    const int t = t0 + ty * 4 + i;
    const int ob = o0 + tx * 4;
    #pragma unroll
    for (int j = 0; j < 4; ++j) {
      out[(size_t)t * E_ + ob + j] =
          __fadd_rn(__fmul_rn(alpha, (float)acc[i][j]), b_out[ob + j]);
    }
  }
}

extern "C" void kernel_launch(void* const* d_in, const int* in_sizes, int n_in,
                              void* d_out, int out_size, void* d_ws, size_t ws_size,
                              hipStream_t stream) {
  const int* hs   = (const int*)d_in[0];
  const int* Wq   = (const int*)d_in[1];
  const int* bq   = (const int*)d_in[2];
  const int* Wk   = (const int*)d_in[3];
  const int* bk   = (const int*)d_in[4];
  const int* Wv   = (const int*)d_in[5];
  const int* bv   = (const int*)d_in[6];
  const int* Wo   = (const int*)d_in[7];
  const float* b_out = (const float*)d_in[8];
  const float* aq   = (const float*)d_in[9];
  const float* btq  = (const float*)d_in[10];
  const float* ak   = (const float*)d_in[11];
  const float* btk  = (const float*)d_in[12];
  const float* av   = (const float*)d_in[13];
  const float* btv  = (const float*)d_in[14];
  const float* aqk  = (const float*)d_in[15];
  const float* apv  = (const float*)d_in[16];
  const float* aout = (const float*)d_in[17];

  const size_t SEG = (size_t)H_ * T_ * D_;          // 8 MB
  char* ws = (char*)d_ws;
  int8_t* Q8    = (int8_t*)ws;
  int8_t* K8    = Q8 + SEG;
  int8_t* VT    = K8 + SEG;                          // transposed V [h][d][t]
  int8_t* attn8 = VT + SEG;                          // aliased with x8
  int8_t* x8    = attn8;
  float*  sinT  = (float*)(ws + 4 * SEG);
  float*  cosT  = sinT + T_ * NF;
  int8_t* Wq8   = (int8_t*)(cosT + T_ * NF);
  int8_t* Wk8   = Wq8 + (size_t)E_ * E_;
  int8_t* Wv8   = Wk8 + (size_t)E_ * E_;
  int8_t* Wo8   = Wv8 + (size_t)E_ * E_;
  const size_t NEED = 4 * SEG + 2 * (size_t)T_ * NF * 4 + 4 * (size_t)E_ * E_;
  const bool big = (ws_size >= NEED);

  sincos_kernel<<<(T_ * NF) / 256, 256, 0, stream>>>(sinT, cosT);

  if (big) {
    repack5_kernel<<<dim3((E_ * E_ / 16) / 256, 5), 256, 0, stream>>>(
        hs, Wq, Wk, Wv, Wo, x8, Wq8, Wk8, Wv8, Wo8);
    qkv_gemm_mfma<<<dim3(T_ / 128, E_ / 128, 3), 256, 0, stream>>>(
        x8, Wq8, bq, Wk8, bk, Wv8, bv, aq, btq, ak, btk, av, btv,
        sinT, cosT, Q8, K8, VT);

    // --- split-s attention. Scratch aliases dead regions:
    //   P1 (16.78 MB)       <- Wq8   (dead after qkv)
    //   P0 (33.55 MB)       <- Wk8+Wv8 (dead after qkv)
    //   mPart/sPart         <- attn8 region (x8 dead; overwritten by combine)
    int*   P1g   = (int*)Wq8;
    int*   P0g   = (int*)Wk8;
    float* mPart = (float*)attn8;                    // 1 MB
    float* sPart = mPart + (size_t)H_ * 32 * 64 * 8; // 1 MB

    attn_ms_chunk<<<dim3(8, 32, H_), 256, 0, stream>>>(Q8, K8, aqk, mPart, sPart);
    attn_pv_chunk<<<dim3(2, 32, H_), 256, 0, stream>>>(
        Q8, K8, VT, aqk, mPart, sPart, P0g, P1g);
    attn_pv_combine<<<(H_ * 32 * 64 * 64) / 256, 256, 0, stream>>>(
        P0g, P1g, apv, attn8);

    out_gemm_mfma<<<dim3(T_ / 128, E_ / 128), 256, 0, stream>>>(
        attn8, Wo8, b_out, aout, (float*)d_out);
  } else {
    qkv_gemm_fb<<<dim3(T_ / 64, E_ / 64, 3), 256, 0, stream>>>(
        hs, Wq, bq, Wk, bk, Wv, bv, aq, btq, ak, btk, av, btv,
        sinT, cosT, Q8, K8, VT);
    attn_mfma<<<dim3(T_ / 64, H_), 256, 0, stream>>>(Q8, K8, VT, aqk, apv, attn8);
    out_gemm_fb<<<dim3(T_ / 64, E_ / 64), 256, 0, stream>>>(
        attn8, Wo, b_out, aout, (float*)d_out);
  }
}